// Round 9
// baseline (516.349 us; speedup 1.0000x reference)
//
#include <hip/hip_runtime.h>
#include <math.h>

typedef short bf16x8 __attribute__((ext_vector_type(8)));
typedef float f32x4  __attribute__((ext_vector_type(4)));
typedef unsigned short u16;
typedef unsigned int   u32;

#define MFMA16 __builtin_amdgcn_mfma_f32_16x16x32_bf16

__device__ __forceinline__ u16 f2b(float x) {   // fp32 -> bf16 RNE
    union { float f; unsigned u; } v; v.f = x;
    unsigned r = v.u + 0x7fffu + ((v.u >> 16) & 1u);
    return (u16)(r >> 16);
}
__device__ __forceinline__ float b2f(u16 h) {
    union { unsigned u; float f; } v; v.u = ((unsigned)h) << 16;
    return v.f;
}
__device__ __forceinline__ float blo(u32 w) {
    union { u32 u; float f; } v; v.u = w << 16; return v.f;
}
__device__ __forceinline__ float bhi(u32 w) {
    union { u32 u; float f; } v; v.u = w & 0xffff0000u; return v.f;
}
// sum 3 packed bf16 pairs in fp32 (order i0+i1+i2), repack bf16
__device__ __forceinline__ u32 add3pack(u32 x, u32 y, u32 z) {
    float lo = blo(x) + blo(y) + blo(z);
    float hi = bhi(x) + bhi(y) + bhi(z);
    return (u32)f2b(lo) | ((u32)f2b(hi) << 16);
}

// ---------------------------------------------------------------------------
// K0: pre-swizzle weights (bf16, B-fragment panel layout) into global ws.
// Panel(kt,nt): 16 n-rows x 40 u16 (pad 32->40). SWZ layout:
//   WB [0,5120) | V1B [5120,15360) | V2B [15360,20480)
// ---------------------------------------------------------------------------
__global__ __launch_bounds__(256) void swizzle_weights(
    const float* __restrict__ Wg, const float* __restrict__ V1g,
    const float* __restrict__ V2g, u16* __restrict__ SWZ)
{
    int idx = blockIdx.x * 256 + threadIdx.x;       // 0..8191
    int k = idx >> 6, n = idx & 63;
    int off = ((k >> 5) * 4 + (n >> 4)) * 640 + (n & 15) * 40 + ((k >> 3) & 3) * 8 + (k & 7);
    SWZ[5120 + off] = f2b(V1g[idx]);
    if (idx < 4096) {
        SWZ[off]         = f2b(Wg[idx]);
        SWZ[15360 + off] = f2b(V2g[idx]);
    }
}

// ---------------------------------------------------------------------------
// K1: node MLP -> hb (bf16) [N,64].  float4 LDS reads: 16 b128 per layer per
// thread instead of 64 scalar b32 (same summation order -> bit-identical h).
// All lanes of a wave read the same h1 address -> LDS broadcast, free.
// ---------------------------------------------------------------------------
__global__ __launch_bounds__(256) void node_mlp_kernel(
    const float* __restrict__ x, const float* __restrict__ u,
    const int* __restrict__ batch,
    const float* __restrict__ W1, const float* __restrict__ b1,
    const float* __restrict__ W2, const float* __restrict__ b2,
    const float* __restrict__ W3, const float* __restrict__ b3,
    u16* __restrict__ hb, int N)
{
    __shared__ float inbuf[4][10];
    __shared__ float h1[4][64];
    __shared__ float h2[4][64];
    const int tid = threadIdx.x;
    const int ni = tid >> 6, f = tid & 63;
    int node = blockIdx.x * 4 + ni;
    if (node >= N) node = N - 1;
    if (f < 6)       inbuf[ni][f] = x[node * 6 + f];
    else if (f < 10) inbuf[ni][f] = u[batch[node] * 4 + (f - 6)];
    __syncthreads();
    float acc = b1[f];
    #pragma unroll
    for (int k = 0; k < 10; ++k) acc = fmaf(inbuf[ni][k], W1[k * 64 + f], acc);
    h1[ni][f] = fmaxf(acc, 0.f);
    __syncthreads();
    acc = b2[f];
    #pragma unroll
    for (int k4 = 0; k4 < 16; ++k4) {
        float4 hv = *(const float4*)&h1[ni][k4 * 4];
        acc = fmaf(hv.x, W2[(k4 * 4 + 0) * 64 + f], acc);
        acc = fmaf(hv.y, W2[(k4 * 4 + 1) * 64 + f], acc);
        acc = fmaf(hv.z, W2[(k4 * 4 + 2) * 64 + f], acc);
        acc = fmaf(hv.w, W2[(k4 * 4 + 3) * 64 + f], acc);
    }
    h2[ni][f] = fmaxf(acc, 0.f);
    __syncthreads();
    acc = b3[f];
    #pragma unroll
    for (int k4 = 0; k4 < 16; ++k4) {
        float4 hv = *(const float4*)&h2[ni][k4 * 4];
        acc = fmaf(hv.x, W3[(k4 * 4 + 0) * 64 + f], acc);
        acc = fmaf(hv.y, W3[(k4 * 4 + 1) * 64 + f], acc);
        acc = fmaf(hv.z, W3[(k4 * 4 + 2) * 64 + f], acc);
        acc = fmaf(hv.w, W3[(k4 * 4 + 3) * 64 + f], acc);
    }
    hb[node * 64 + f] = f2b(acc);
}

// ---------------------------------------------------------------------------
// K2: segment boundaries (batch_hyper sorted)
// ---------------------------------------------------------------------------
__global__ __launch_bounds__(256) void seg_bounds_kernel(
    const int* __restrict__ bh, int E, int G, int* __restrict__ seg_start)
{
    int g = blockIdx.x * blockDim.x + threadIdx.x;
    if (g > G) return;
    int lo = 0, hi = E;
    while (lo < hi) {
        int mid = (lo + hi) >> 1;
        if (bh[mid] < g) lo = mid + 1; else hi = mid;
    }
    seg_start[g] = lo;
}

// ---------------------------------------------------------------------------
// K3: gather + Xh write + softmax denominators + out[E..2E) writes.
// Standalone at max occupancy (R8 lesson: do NOT fuse with the MFMA phase).
// j unrolled x8 -> 24 hidx + 24 hb gathers in flight per wave (R6 had 12).
// Per-lane edge set and ascending order identical to R6 -> bit-identical.
// exp of the bf16-ROUNDED sum (matches K4's A-frags exactly).
// ---------------------------------------------------------------------------
__global__ __launch_bounds__(256) void gather_stats_kernel(
    const u16* __restrict__ hb, const int* __restrict__ hidx,
    const int* __restrict__ seg_start,
    u16* __restrict__ Xh, float* __restrict__ Sinv,
    float* __restrict__ out, int E)
{
    __shared__ float ps[4][16][4];
    const int tid = threadIdx.x, lane = tid & 63, wid = tid >> 6;
    const int sub = lane >> 4, cl = lane & 15;
    const int g = blockIdx.x;
    const int e0 = seg_start[g], e1 = seg_start[g + 1];
    if (e1 <= e0) return;                       // uniform across block
    const int e1m1 = e1 - 1;
    const float gf = (float)g;

    for (int e = e0 + tid; e < e1; e += 256) out[E + e] = gf;   // coalesced

    float s0 = 0.f, s1 = 0.f, s2 = 0.f, s3 = 0.f;
    for (int e = e0 + wid * 4 + sub; e < e1; e += 128) {
        #pragma unroll
        for (int j = 0; j < 8; ++j) {
            int ee = e + j * 16;
            int ec = min(ee, e1m1);
            int i0 = hidx[ec], i1 = hidx[E + ec], i2 = hidx[2 * E + ec];
            uint2 A0 = *(const uint2*)(hb + (size_t)i0 * 64 + cl * 4);
            uint2 A1 = *(const uint2*)(hb + (size_t)i1 * 64 + cl * 4);
            uint2 A2 = *(const uint2*)(hb + (size_t)i2 * 64 + cl * 4);
            u32 wx = add3pack(A0.x, A1.x, A2.x);
            u32 wy = add3pack(A0.y, A1.y, A2.y);
            if (ee < e1) {
                uint2 W; W.x = wx; W.y = wy;
                *(uint2*)(Xh + (size_t)ee * 64 + cl * 4) = W;
                s0 += __expf(blo(wx)); s1 += __expf(bhi(wx));
                s2 += __expf(blo(wy)); s3 += __expf(bhi(wy));
            }
        }
    }
    // reduce over sub (lane bits 4,5) then over waves
    s0 += __shfl_xor(s0, 16); s0 += __shfl_xor(s0, 32);
    s1 += __shfl_xor(s1, 16); s1 += __shfl_xor(s1, 32);
    s2 += __shfl_xor(s2, 16); s2 += __shfl_xor(s2, 32);
    s3 += __shfl_xor(s3, 16); s3 += __shfl_xor(s3, 32);
    if (lane < 16) {
        ps[wid][cl][0] = s0; ps[wid][cl][1] = s1;
        ps[wid][cl][2] = s2; ps[wid][cl][3] = s3;
    }
    __syncthreads();
    if (tid < 64) {
        int c4 = tid >> 2, cc = tid & 3;
        float S = ps[0][c4][cc] + ps[1][c4][cc] + ps[2][c4][cc] + ps[3][c4][cc];
        Sinv[g * 64 + tid] = 1.f / S;
    }
}

// ---------------------------------------------------------------------------
// K4: MFMA chain (R6-verified streaming loop) at higher occupancy:
// 512-thread blocks, TWO segments per block (waves 0-3 -> seg 2b, 4-7 ->
// seg 2b+1) sharing one 40KB SW staging. LDS 59392 B -> 2 blocks/CU =
// 16 waves (R6 had 12). Xh read streaming with 1-deep prefetch (R7 lesson:
// never re-gather randomly here). All weights in LDS (R5 lesson).
// xv via identity-MFMA (exact). XT C->A transposes, wave-private.
// ---------------------------------------------------------------------------
__global__ __launch_bounds__(512, 4) void mfma_seg_kernel(
    const u16* __restrict__ Xh, const int* __restrict__ seg_start,
    const u16* __restrict__ SWZ, const float* __restrict__ Sinv,
    const float* __restrict__ c1g, const float* __restrict__ c2g,
    const float* __restrict__ V3g, const float* __restrict__ c3g,
    float* __restrict__ out, int E, int G)
{
    __shared__ u16 SW[20480];          // WB[0,5120)+V1B[5120,15360)+V2B[15360,20480)
    __shared__ u16 XT_all[8][16 * 72]; // per-wave transpose tile

    const int tid = threadIdx.x, lane = tid & 63, wid = tid >> 6;  // wid 0..7
    const int nl = lane & 15, rq = lane >> 4;
    const int wl = wid & 3;
    const int g = blockIdx.x * 2 + (wid >> 2);

    {   // stage pre-swizzled W+V1+V2: 40960 B = 2560 uint4 over 512 threads
        const uint4* src = (const uint4*)SWZ;
        uint4* dst = (uint4*)SW;
        for (int i = tid; i < 2560; i += 512) dst[i] = src[i];
    }
    __syncthreads();                    // only barrier; safe to return after

    if (g >= G) return;
    const int e0 = seg_start[g], e1 = seg_start[g + 1];
    const int L = e1 - e0;
    if (L <= 0) return;
    const int e1m1 = e1 - 1;

    const u16* WB  = SW;
    const u16* V1B = SW + 5120;
    const u16* V2B = SW + 15360;

    // identity B-frags for X C-layout redistribution (exact in bf16)
    bf16x8 I0, I1;
    #pragma unroll
    for (int j = 0; j < 8; ++j) {
        I0[j] = (rq * 8 + j == nl)      ? (short)0x3F80 : (short)0;
        I1[j] = (rq * 8 + j == nl + 16) ? (short)0x3F80 : (short)0;
    }

    float dinvv[4], c1v[4], c2v[4], v3v[4];
    #pragma unroll
    for (int nt = 0; nt < 4; ++nt) {
        int col = nt * 16 + nl;
        dinvv[nt] = Sinv[g * 64 + col];
        c1v[nt]   = c1g[col];
        c2v[nt]   = c2g[col];
        v3v[nt]   = V3g[col];
    }
    const float c3s = c3g[0];
    u16* XT = XT_all[wid];
    const f32x4 zf = {0.f, 0.f, 0.f, 0.f};

    int t = wl;
    bf16x8 a0 = {}, a1 = {};
    if (t * 16 < L) {
        const u16* xp = Xh + (size_t)min(e0 + t * 16 + nl, e1m1) * 64 + rq * 8;
        a0 = *(const bf16x8*)(xp);
        a1 = *(const bf16x8*)(xp + 32);
    }

    for (; t * 16 < L; t += 4) {
        const int eB = e0 + t * 16;
        const int tn = t + 4;
        bf16x8 n0 = {}, n1 = {};
        if (tn * 16 < L) {  // prefetch next tile (wave-uniform branch)
            const u16* xp = Xh + (size_t)min(e0 + tn * 16 + nl, e1m1) * 64 + rq * 8;
            n0 = *(const bf16x8*)(xp);
            n1 = *(const bf16x8*)(xp + 32);
        }

        // xv in C-layout via identity MFMA (matrix pipe, overlaps layer W)
        f32x4 xc[4];
        xc[0] = MFMA16(a0, I0, zf, 0, 0, 0);
        xc[1] = MFMA16(a0, I1, zf, 0, 0, 0);
        xc[2] = MFMA16(a1, I0, zf, 0, 0, 0);
        xc[3] = MFMA16(a1, I1, zf, 0, 0, 0);

        // ---- layer W: acc = X @ W ----
        f32x4 acc[4] = {zf, zf, zf, zf};
        #pragma unroll
        for (int nt = 0; nt < 4; ++nt) {
            bf16x8 b0 = *(const bf16x8*)(WB + (0 * 4 + nt) * 640 + nl * 40 + rq * 8);
            acc[nt] = MFMA16(a0, b0, acc[nt], 0, 0, 0);
            bf16x8 b1 = *(const bf16x8*)(WB + (1 * 4 + nt) * 640 + nl * 40 + rq * 8);
            acc[nt] = MFMA16(a1, b1, acc[nt], 0, 0, 0);
        }
        // epilogue: Xhat = exp(xv)*dinv * relu(acc) -> XT
        #pragma unroll
        for (int nt = 0; nt < 4; ++nt) {
            #pragma unroll
            for (int r = 0; r < 4; ++r) {
                float coef = __expf(xc[nt][r]) * dinvv[nt];
                XT[(rq * 4 + r) * 72 + nt * 16 + nl] =
                    f2b(coef * fmaxf(acc[nt][r], 0.f));
            }
        }
        bf16x8 x2 = *(const bf16x8*)(XT + nl * 72 + rq * 8);
        bf16x8 x3 = *(const bf16x8*)(XT + nl * 72 + 32 + rq * 8);

        // ---- layer V1: acc2 = [X ; Xhat] @ V1 + c1 ----
        f32x4 acc2[4];
        #pragma unroll
        for (int nt = 0; nt < 4; ++nt) {
            acc2[nt][0] = c1v[nt]; acc2[nt][1] = c1v[nt];
            acc2[nt][2] = c1v[nt]; acc2[nt][3] = c1v[nt];
        }
        #pragma unroll
        for (int nt = 0; nt < 4; ++nt) {
            bf16x8 b0 = *(const bf16x8*)(V1B + (0 * 4 + nt) * 640 + nl * 40 + rq * 8);
            acc2[nt] = MFMA16(a0, b0, acc2[nt], 0, 0, 0);
            bf16x8 b1 = *(const bf16x8*)(V1B + (1 * 4 + nt) * 640 + nl * 40 + rq * 8);
            acc2[nt] = MFMA16(a1, b1, acc2[nt], 0, 0, 0);
        }
        #pragma unroll
        for (int nt = 0; nt < 4; ++nt) {
            bf16x8 b2 = *(const bf16x8*)(V1B + (2 * 4 + nt) * 640 + nl * 40 + rq * 8);
            acc2[nt] = MFMA16(x2, b2, acc2[nt], 0, 0, 0);
            bf16x8 b3 = *(const bf16x8*)(V1B + (3 * 4 + nt) * 640 + nl * 40 + rq * 8);
            acc2[nt] = MFMA16(x3, b3, acc2[nt], 0, 0, 0);
        }
        // epilogue: O1 = relu(acc2) -> XT
        #pragma unroll
        for (int nt = 0; nt < 4; ++nt) {
            #pragma unroll
            for (int r = 0; r < 4; ++r)
                XT[(rq * 4 + r) * 72 + nt * 16 + nl] = f2b(fmaxf(acc2[nt][r], 0.f));
        }
        bf16x8 o0 = *(const bf16x8*)(XT + nl * 72 + rq * 8);
        bf16x8 o1 = *(const bf16x8*)(XT + nl * 72 + 32 + rq * 8);

        // ---- layer V2: acc3 = O1 @ V2 + c2 (B-frags from LDS) ----
        f32x4 acc3[4];
        #pragma unroll
        for (int nt = 0; nt < 4; ++nt) {
            acc3[nt][0] = c2v[nt]; acc3[nt][1] = c2v[nt];
            acc3[nt][2] = c2v[nt]; acc3[nt][3] = c2v[nt];
        }
        #pragma unroll
        for (int nt = 0; nt < 4; ++nt) {
            bf16x8 b0 = *(const bf16x8*)(V2B + (0 * 4 + nt) * 640 + nl * 40 + rq * 8);
            acc3[nt] = MFMA16(o0, b0, acc3[nt], 0, 0, 0);
            bf16x8 b1 = *(const bf16x8*)(V2B + (1 * 4 + nt) * 640 + nl * 40 + rq * 8);
            acc3[nt] = MFMA16(o1, b1, acc3[nt], 0, 0, 0);
        }

        // ---- V3 + sigmoid ----
        float sr[4];
        #pragma unroll
        for (int r = 0; r < 4; ++r) {
            float v = 0.f;
            #pragma unroll
            for (int nt = 0; nt < 4; ++nt)
                v = fmaf(fmaxf(acc3[nt][r], 0.f), v3v[nt], v);
            v += __shfl_xor(v, 1);
            v += __shfl_xor(v, 2);
            v += __shfl_xor(v, 4);
            v += __shfl_xor(v, 8);
            sr[r] = v;
        }
        if (nl == 0) {
            #pragma unroll
            for (int r = 0; r < 4; ++r) {
                int e = eB + rq * 4 + r;
                if (e < e1) out[e] = 1.f / (1.f + __expf(-(sr[r] + c3s)));
            }
        }
        a0 = n0; a1 = n1;
    }
}

// ---------------------------------------------------------------------------
extern "C" void kernel_launch(void* const* d_in, const int* in_sizes, int n_in,
                              void* d_out, int out_size, void* d_ws, size_t ws_size,
                              hipStream_t stream) {
    const float* x     = (const float*)d_in[0];
    const float* u     = (const float*)d_in[1];
    const int*   batch = (const int*)  d_in[2];
    const int*   hidx  = (const int*)  d_in[3];
    const int*   bh    = (const int*)  d_in[4];
    const float* W1 = (const float*)d_in[6];
    const float* b1 = (const float*)d_in[7];
    const float* W2 = (const float*)d_in[8];
    const float* b2 = (const float*)d_in[9];
    const float* W3 = (const float*)d_in[10];
    const float* b3 = (const float*)d_in[11];
    const float* Wg = (const float*)d_in[12];
    const float* V1 = (const float*)d_in[13];
    const float* c1 = (const float*)d_in[14];
    const float* V2 = (const float*)d_in[15];
    const float* c2 = (const float*)d_in[16];
    const float* V3 = (const float*)d_in[17];
    const float* c3 = (const float*)d_in[18];

    const int N = in_sizes[0] / 6;
    const int G = in_sizes[1] / 4;
    const int E = in_sizes[4];

    // ws layout
    char* ws = (char*)d_ws;
    size_t off = 0;
    u16* hb = (u16*)(ws + off);            off += (size_t)N * 64 * 2;
    int* seg_start = (int*)(ws + off);     off += ((size_t)G + 1) * 4;
    off = (off + 255) & ~(size_t)255;
    u16* SWZ = (u16*)(ws + off);           off += 20480 * 2;
    float* Sinv = (float*)(ws + off);      off += (size_t)G * 64 * 4;
    off = (off + 255) & ~(size_t)255;
    u16* Xh = (u16*)(ws + off);            off += (size_t)E * 64 * 2;
    float* out = (float*)d_out;

    swizzle_weights<<<32, 256, 0, stream>>>(Wg, V1, V2, SWZ);
    node_mlp_kernel<<<(N + 3) / 4, 256, 0, stream>>>(
        x, u, batch, W1, b1, W2, b2, W3, b3, hb, N);
    seg_bounds_kernel<<<(G + 256) / 256, 256, 0, stream>>>(bh, E, G, seg_start);
    gather_stats_kernel<<<G, 256, 0, stream>>>(hb, hidx, seg_start, Xh, Sinv, out, E);
    mfma_seg_kernel<<<(G + 1) / 2, 512, 0, stream>>>(
        Xh, seg_start, SWZ, Sinv, c1, c2, V3, c3, out, E, G);
}

// Round 10
// 379.693 us; speedup vs baseline: 1.3599x; 1.3599x over previous
//
#include <hip/hip_runtime.h>
#include <math.h>

typedef short bf16x8 __attribute__((ext_vector_type(8)));
typedef float f32x4  __attribute__((ext_vector_type(4)));
typedef unsigned short u16;
typedef unsigned int   u32;

#define MFMA16 __builtin_amdgcn_mfma_f32_16x16x32_bf16

__device__ __forceinline__ u16 f2b(float x) {   // fp32 -> bf16 RNE
    union { float f; unsigned u; } v; v.f = x;
    unsigned r = v.u + 0x7fffu + ((v.u >> 16) & 1u);
    return (u16)(r >> 16);
}
__device__ __forceinline__ float b2f(u16 h) {
    union { unsigned u; float f; } v; v.u = ((unsigned)h) << 16;
    return v.f;
}
__device__ __forceinline__ float blo(u32 w) {
    union { u32 u; float f; } v; v.u = w << 16; return v.f;
}
__device__ __forceinline__ float bhi(u32 w) {
    union { u32 u; float f; } v; v.u = w & 0xffff0000u; return v.f;
}
// sum 3 packed bf16 pairs in fp32 (order i0+i1+i2), repack bf16
__device__ __forceinline__ u32 add3pack(u32 x, u32 y, u32 z) {
    float lo = blo(x) + blo(y) + blo(z);
    float hi = bhi(x) + bhi(y) + bhi(z);
    return (u32)f2b(lo) | ((u32)f2b(hi) << 16);
}

// ---------------------------------------------------------------------------
// K0: pre-swizzle weights (bf16, B-fragment panel layout) into global ws.
// Panel(kt,nt): 16 n-rows x 40 u16 (pad 32->40). SWZ layout:
//   WB [0,5120) | V1B [5120,15360) | V2B [15360,20480)
// ---------------------------------------------------------------------------
__global__ __launch_bounds__(256) void swizzle_weights(
    const float* __restrict__ Wg, const float* __restrict__ V1g,
    const float* __restrict__ V2g, u16* __restrict__ SWZ)
{
    int idx = blockIdx.x * 256 + threadIdx.x;       // 0..8191
    int k = idx >> 6, n = idx & 63;
    int off = ((k >> 5) * 4 + (n >> 4)) * 640 + (n & 15) * 40 + ((k >> 3) & 3) * 8 + (k & 7);
    SWZ[5120 + off] = f2b(V1g[idx]);
    if (idx < 4096) {
        SWZ[off]         = f2b(Wg[idx]);
        SWZ[15360 + off] = f2b(V2g[idx]);
    }
}

// ---------------------------------------------------------------------------
// K1: node MLP -> hb (bf16) [N,64].  float4 LDS reads (R9-verified):
// 16 b128 per layer per thread instead of 64 scalar b32; same summation
// order -> bit-identical h. Same-address reads broadcast (free).
// ---------------------------------------------------------------------------
__global__ __launch_bounds__(256) void node_mlp_kernel(
    const float* __restrict__ x, const float* __restrict__ u,
    const int* __restrict__ batch,
    const float* __restrict__ W1, const float* __restrict__ b1,
    const float* __restrict__ W2, const float* __restrict__ b2,
    const float* __restrict__ W3, const float* __restrict__ b3,
    u16* __restrict__ hb, int N)
{
    __shared__ float inbuf[4][10];
    __shared__ float h1[4][64];
    __shared__ float h2[4][64];
    const int tid = threadIdx.x;
    const int ni = tid >> 6, f = tid & 63;
    int node = blockIdx.x * 4 + ni;
    if (node >= N) node = N - 1;
    if (f < 6)       inbuf[ni][f] = x[node * 6 + f];
    else if (f < 10) inbuf[ni][f] = u[batch[node] * 4 + (f - 6)];
    __syncthreads();
    float acc = b1[f];
    #pragma unroll
    for (int k = 0; k < 10; ++k) acc = fmaf(inbuf[ni][k], W1[k * 64 + f], acc);
    h1[ni][f] = fmaxf(acc, 0.f);
    __syncthreads();
    acc = b2[f];
    #pragma unroll
    for (int k4 = 0; k4 < 16; ++k4) {
        float4 hv = *(const float4*)&h1[ni][k4 * 4];
        acc = fmaf(hv.x, W2[(k4 * 4 + 0) * 64 + f], acc);
        acc = fmaf(hv.y, W2[(k4 * 4 + 1) * 64 + f], acc);
        acc = fmaf(hv.z, W2[(k4 * 4 + 2) * 64 + f], acc);
        acc = fmaf(hv.w, W2[(k4 * 4 + 3) * 64 + f], acc);
    }
    h2[ni][f] = fmaxf(acc, 0.f);
    __syncthreads();
    acc = b3[f];
    #pragma unroll
    for (int k4 = 0; k4 < 16; ++k4) {
        float4 hv = *(const float4*)&h2[ni][k4 * 4];
        acc = fmaf(hv.x, W3[(k4 * 4 + 0) * 64 + f], acc);
        acc = fmaf(hv.y, W3[(k4 * 4 + 1) * 64 + f], acc);
        acc = fmaf(hv.z, W3[(k4 * 4 + 2) * 64 + f], acc);
        acc = fmaf(hv.w, W3[(k4 * 4 + 3) * 64 + f], acc);
    }
    hb[node * 64 + f] = f2b(acc);
}

// ---------------------------------------------------------------------------
// K2: segment boundaries (batch_hyper sorted)
// ---------------------------------------------------------------------------
__global__ __launch_bounds__(256) void seg_bounds_kernel(
    const int* __restrict__ bh, int E, int G, int* __restrict__ seg_start)
{
    int g = blockIdx.x * blockDim.x + threadIdx.x;
    if (g > G) return;
    int lo = 0, hi = E;
    while (lo < hi) {
        int mid = (lo + hi) >> 1;
        if (bh[mid] < g) lo = mid + 1; else hi = mid;
    }
    seg_start[g] = lo;
}

// ---------------------------------------------------------------------------
// K3: gather + Xh write + softmax denominators + out[E..2E) writes.
// Standalone at max occupancy (R8 lesson: do NOT fuse with the MFMA phase).
// j unrolled x8 (R9-verified): 24 hidx + 24 hb gathers in flight per wave.
// exp of the bf16-ROUNDED sum (matches K4's A-frags exactly).
// ---------------------------------------------------------------------------
__global__ __launch_bounds__(256) void gather_stats_kernel(
    const u16* __restrict__ hb, const int* __restrict__ hidx,
    const int* __restrict__ seg_start,
    u16* __restrict__ Xh, float* __restrict__ Sinv,
    float* __restrict__ out, int E)
{
    __shared__ float ps[4][16][4];
    const int tid = threadIdx.x, lane = tid & 63, wid = tid >> 6;
    const int sub = lane >> 4, cl = lane & 15;
    const int g = blockIdx.x;
    const int e0 = seg_start[g], e1 = seg_start[g + 1];
    if (e1 <= e0) return;                       // uniform across block
    const int e1m1 = e1 - 1;
    const float gf = (float)g;

    for (int e = e0 + tid; e < e1; e += 256) out[E + e] = gf;   // coalesced

    float s0 = 0.f, s1 = 0.f, s2 = 0.f, s3 = 0.f;
    for (int e = e0 + wid * 4 + sub; e < e1; e += 128) {
        #pragma unroll
        for (int j = 0; j < 8; ++j) {
            int ee = e + j * 16;
            int ec = min(ee, e1m1);
            int i0 = hidx[ec], i1 = hidx[E + ec], i2 = hidx[2 * E + ec];
            uint2 A0 = *(const uint2*)(hb + (size_t)i0 * 64 + cl * 4);
            uint2 A1 = *(const uint2*)(hb + (size_t)i1 * 64 + cl * 4);
            uint2 A2 = *(const uint2*)(hb + (size_t)i2 * 64 + cl * 4);
            u32 wx = add3pack(A0.x, A1.x, A2.x);
            u32 wy = add3pack(A0.y, A1.y, A2.y);
            if (ee < e1) {
                uint2 W; W.x = wx; W.y = wy;
                *(uint2*)(Xh + (size_t)ee * 64 + cl * 4) = W;
                s0 += __expf(blo(wx)); s1 += __expf(bhi(wx));
                s2 += __expf(blo(wy)); s3 += __expf(bhi(wy));
            }
        }
    }
    // reduce over sub (lane bits 4,5) then over waves
    s0 += __shfl_xor(s0, 16); s0 += __shfl_xor(s0, 32);
    s1 += __shfl_xor(s1, 16); s1 += __shfl_xor(s1, 32);
    s2 += __shfl_xor(s2, 16); s2 += __shfl_xor(s2, 32);
    s3 += __shfl_xor(s3, 16); s3 += __shfl_xor(s3, 32);
    if (lane < 16) {
        ps[wid][cl][0] = s0; ps[wid][cl][1] = s1;
        ps[wid][cl][2] = s2; ps[wid][cl][3] = s3;
    }
    __syncthreads();
    if (tid < 64) {
        int c4 = tid >> 2, cc = tid & 3;
        float S = ps[0][c4][cc] + ps[1][c4][cc] + ps[2][c4][cc] + ps[3][c4][cc];
        Sinv[g * 64 + tid] = 1.f / S;
    }
}

// ---------------------------------------------------------------------------
// K4: MFMA chain — EXACT R6 configuration (verified 186us / VGPR 84 /
// FETCH 303MB / no spill). 256-thread blocks, one segment per block,
// __launch_bounds__(256,3). R9 lesson: 512-thread blocks put the allocator
// in a 64-VGPR mode that spills the streaming a-frags to scratch
// (+523MB FETCH, 2x dur) — do not use 512-thread blocks here.
// All weights in LDS (R5 lesson). Xh streamed with 1-deep prefetch
// (R7 lesson: never re-gather randomly here). xv via identity-MFMA (exact).
// LDS: 40960(SW) + 9216(XT) = 50176 B -> 3 blocks/CU.
// ---------------------------------------------------------------------------
__global__ __launch_bounds__(256, 3) void mfma_seg_kernel(
    const u16* __restrict__ Xh, const int* __restrict__ seg_start,
    const u16* __restrict__ SWZ, const float* __restrict__ Sinv,
    const float* __restrict__ c1g, const float* __restrict__ c2g,
    const float* __restrict__ V3g, const float* __restrict__ c3g,
    float* __restrict__ out, int E)
{
    __shared__ u16 SW[20480];          // WB[0,5120)+V1B[5120,15360)+V2B[15360,20480)
    __shared__ u16 XT_all[4][16 * 72]; // per-wave transpose tile

    const int tid = threadIdx.x, lane = tid & 63, wid = tid >> 6;
    const int nl = lane & 15, rq = lane >> 4;
    const int g = blockIdx.x;
    const int e0 = seg_start[g], e1 = seg_start[g + 1];
    const int L = e1 - e0;
    if (L <= 0) return;
    const int e1m1 = e1 - 1;

    {   // stage pre-swizzled W+V1+V2: 40960 B = 2560 uint4
        const uint4* src = (const uint4*)SWZ;
        uint4* dst = (uint4*)SW;
        for (int i = tid; i < 2560; i += 256) dst[i] = src[i];
    }
    __syncthreads();
    const u16* WB  = SW;
    const u16* V1B = SW + 5120;
    const u16* V2B = SW + 15360;

    // identity B-frags for X C-layout redistribution (exact in bf16)
    bf16x8 I0, I1;
    #pragma unroll
    for (int j = 0; j < 8; ++j) {
        I0[j] = (rq * 8 + j == nl)      ? (short)0x3F80 : (short)0;
        I1[j] = (rq * 8 + j == nl + 16) ? (short)0x3F80 : (short)0;
    }

    float dinvv[4], c1v[4], c2v[4], v3v[4];
    #pragma unroll
    for (int nt = 0; nt < 4; ++nt) {
        int col = nt * 16 + nl;
        dinvv[nt] = Sinv[g * 64 + col];
        c1v[nt]   = c1g[col];
        c2v[nt]   = c2g[col];
        v3v[nt]   = V3g[col];
    }
    const float c3s = c3g[0];
    u16* XT = XT_all[wid];
    const f32x4 zf = {0.f, 0.f, 0.f, 0.f};

    int t = wid;
    bf16x8 a0 = {}, a1 = {};
    if (t * 16 < L) {
        const u16* xp = Xh + (size_t)min(e0 + t * 16 + nl, e1m1) * 64 + rq * 8;
        a0 = *(const bf16x8*)(xp);
        a1 = *(const bf16x8*)(xp + 32);
    }

    for (; t * 16 < L; t += 4) {
        const int eB = e0 + t * 16;
        const int tn = t + 4;
        bf16x8 n0 = {}, n1 = {};
        if (tn * 16 < L) {  // prefetch next tile (wave-uniform branch)
            const u16* xp = Xh + (size_t)min(e0 + tn * 16 + nl, e1m1) * 64 + rq * 8;
            n0 = *(const bf16x8*)(xp);
            n1 = *(const bf16x8*)(xp + 32);
        }

        // xv in C-layout via identity MFMA (matrix pipe, overlaps layer W)
        f32x4 xc[4];
        xc[0] = MFMA16(a0, I0, zf, 0, 0, 0);
        xc[1] = MFMA16(a0, I1, zf, 0, 0, 0);
        xc[2] = MFMA16(a1, I0, zf, 0, 0, 0);
        xc[3] = MFMA16(a1, I1, zf, 0, 0, 0);

        // ---- layer W: acc = X @ W ----
        f32x4 acc[4] = {zf, zf, zf, zf};
        #pragma unroll
        for (int nt = 0; nt < 4; ++nt) {
            bf16x8 b0 = *(const bf16x8*)(WB + (0 * 4 + nt) * 640 + nl * 40 + rq * 8);
            acc[nt] = MFMA16(a0, b0, acc[nt], 0, 0, 0);
            bf16x8 b1 = *(const bf16x8*)(WB + (1 * 4 + nt) * 640 + nl * 40 + rq * 8);
            acc[nt] = MFMA16(a1, b1, acc[nt], 0, 0, 0);
        }
        // epilogue: Xhat = exp(xv)*dinv * relu(acc) -> XT
        #pragma unroll
        for (int nt = 0; nt < 4; ++nt) {
            #pragma unroll
            for (int r = 0; r < 4; ++r) {
                float coef = __expf(xc[nt][r]) * dinvv[nt];
                XT[(rq * 4 + r) * 72 + nt * 16 + nl] =
                    f2b(coef * fmaxf(acc[nt][r], 0.f));
            }
        }
        bf16x8 x2 = *(const bf16x8*)(XT + nl * 72 + rq * 8);
        bf16x8 x3 = *(const bf16x8*)(XT + nl * 72 + 32 + rq * 8);

        // ---- layer V1: acc2 = [X ; Xhat] @ V1 + c1 ----
        f32x4 acc2[4];
        #pragma unroll
        for (int nt = 0; nt < 4; ++nt) {
            acc2[nt][0] = c1v[nt]; acc2[nt][1] = c1v[nt];
            acc2[nt][2] = c1v[nt]; acc2[nt][3] = c1v[nt];
        }
        #pragma unroll
        for (int nt = 0; nt < 4; ++nt) {
            bf16x8 b0 = *(const bf16x8*)(V1B + (0 * 4 + nt) * 640 + nl * 40 + rq * 8);
            acc2[nt] = MFMA16(a0, b0, acc2[nt], 0, 0, 0);
            bf16x8 b1 = *(const bf16x8*)(V1B + (1 * 4 + nt) * 640 + nl * 40 + rq * 8);
            acc2[nt] = MFMA16(a1, b1, acc2[nt], 0, 0, 0);
        }
        #pragma unroll
        for (int nt = 0; nt < 4; ++nt) {
            bf16x8 b2 = *(const bf16x8*)(V1B + (2 * 4 + nt) * 640 + nl * 40 + rq * 8);
            acc2[nt] = MFMA16(x2, b2, acc2[nt], 0, 0, 0);
            bf16x8 b3 = *(const bf16x8*)(V1B + (3 * 4 + nt) * 640 + nl * 40 + rq * 8);
            acc2[nt] = MFMA16(x3, b3, acc2[nt], 0, 0, 0);
        }
        // epilogue: O1 = relu(acc2) -> XT
        #pragma unroll
        for (int nt = 0; nt < 4; ++nt) {
            #pragma unroll
            for (int r = 0; r < 4; ++r)
                XT[(rq * 4 + r) * 72 + nt * 16 + nl] = f2b(fmaxf(acc2[nt][r], 0.f));
        }
        bf16x8 o0 = *(const bf16x8*)(XT + nl * 72 + rq * 8);
        bf16x8 o1 = *(const bf16x8*)(XT + nl * 72 + 32 + rq * 8);

        // ---- layer V2: acc3 = O1 @ V2 + c2 (B-frags from LDS) ----
        f32x4 acc3[4];
        #pragma unroll
        for (int nt = 0; nt < 4; ++nt) {
            acc3[nt][0] = c2v[nt]; acc3[nt][1] = c2v[nt];
            acc3[nt][2] = c2v[nt]; acc3[nt][3] = c2v[nt];
        }
        #pragma unroll
        for (int nt = 0; nt < 4; ++nt) {
            bf16x8 b0 = *(const bf16x8*)(V2B + (0 * 4 + nt) * 640 + nl * 40 + rq * 8);
            acc3[nt] = MFMA16(o0, b0, acc3[nt], 0, 0, 0);
            bf16x8 b1 = *(const bf16x8*)(V2B + (1 * 4 + nt) * 640 + nl * 40 + rq * 8);
            acc3[nt] = MFMA16(o1, b1, acc3[nt], 0, 0, 0);
        }

        // ---- V3 + sigmoid ----
        float sr[4];
        #pragma unroll
        for (int r = 0; r < 4; ++r) {
            float v = 0.f;
            #pragma unroll
            for (int nt = 0; nt < 4; ++nt)
                v = fmaf(fmaxf(acc3[nt][r], 0.f), v3v[nt], v);
            v += __shfl_xor(v, 1);
            v += __shfl_xor(v, 2);
            v += __shfl_xor(v, 4);
            v += __shfl_xor(v, 8);
            sr[r] = v;
        }
        if (nl == 0) {
            #pragma unroll
            for (int r = 0; r < 4; ++r) {
                int e = eB + rq * 4 + r;
                if (e < e1) out[e] = 1.f / (1.f + __expf(-(sr[r] + c3s)));
            }
        }
        a0 = n0; a1 = n1;
    }
}

// ---------------------------------------------------------------------------
extern "C" void kernel_launch(void* const* d_in, const int* in_sizes, int n_in,
                              void* d_out, int out_size, void* d_ws, size_t ws_size,
                              hipStream_t stream) {
    const float* x     = (const float*)d_in[0];
    const float* u     = (const float*)d_in[1];
    const int*   batch = (const int*)  d_in[2];
    const int*   hidx  = (const int*)  d_in[3];
    const int*   bh    = (const int*)  d_in[4];
    const float* W1 = (const float*)d_in[6];
    const float* b1 = (const float*)d_in[7];
    const float* W2 = (const float*)d_in[8];
    const float* b2 = (const float*)d_in[9];
    const float* W3 = (const float*)d_in[10];
    const float* b3 = (const float*)d_in[11];
    const float* Wg = (const float*)d_in[12];
    const float* V1 = (const float*)d_in[13];
    const float* c1 = (const float*)d_in[14];
    const float* V2 = (const float*)d_in[15];
    const float* c2 = (const float*)d_in[16];
    const float* V3 = (const float*)d_in[17];
    const float* c3 = (const float*)d_in[18];

    const int N = in_sizes[0] / 6;
    const int G = in_sizes[1] / 4;
    const int E = in_sizes[4];

    // ws layout
    char* ws = (char*)d_ws;
    size_t off = 0;
    u16* hb = (u16*)(ws + off);            off += (size_t)N * 64 * 2;
    int* seg_start = (int*)(ws + off);     off += ((size_t)G + 1) * 4;
    off = (off + 255) & ~(size_t)255;
    u16* SWZ = (u16*)(ws + off);           off += 20480 * 2;
    float* Sinv = (float*)(ws + off);      off += (size_t)G * 64 * 4;
    off = (off + 255) & ~(size_t)255;
    u16* Xh = (u16*)(ws + off);            off += (size_t)E * 64 * 2;
    float* out = (float*)d_out;

    swizzle_weights<<<32, 256, 0, stream>>>(Wg, V1, V2, SWZ);
    node_mlp_kernel<<<(N + 3) / 4, 256, 0, stream>>>(
        x, u, batch, W1, b1, W2, b2, W3, b3, hb, N);
    seg_bounds_kernel<<<(G + 256) / 256, 256, 0, stream>>>(bh, E, G, seg_start);
    gather_stats_kernel<<<G, 256, 0, stream>>>(hb, hidx, seg_start, Xh, Sinv, out, E);
    mfma_seg_kernel<<<G, 256, 0, stream>>>(
        Xh, seg_start, SWZ, Sinv, c1, c2, V3, c3, out, E);
}

// Round 11
// 280.129 us; speedup vs baseline: 1.8433x; 1.3554x over previous
//
#include <hip/hip_runtime.h>
#include <math.h>

typedef short bf16x8 __attribute__((ext_vector_type(8)));
typedef float f32x4  __attribute__((ext_vector_type(4)));
typedef unsigned short u16;
typedef unsigned int   u32;

#define MFMA16 __builtin_amdgcn_mfma_f32_16x16x32_bf16

__device__ __forceinline__ u16 f2b(float x) {   // fp32 -> bf16 RNE
    union { float f; unsigned u; } v; v.f = x;
    unsigned r = v.u + 0x7fffu + ((v.u >> 16) & 1u);
    return (u16)(r >> 16);
}
__device__ __forceinline__ float b2f(u16 h) {
    union { unsigned u; float f; } v; v.u = ((unsigned)h) << 16;
    return v.f;
}
__device__ __forceinline__ float blo(u32 w) {
    union { u32 u; float f; } v; v.u = w << 16; return v.f;
}
__device__ __forceinline__ float bhi(u32 w) {
    union { u32 u; float f; } v; v.u = w & 0xffff0000u; return v.f;
}
// sum 3 packed bf16 pairs in fp32 (order i0+i1+i2), repack bf16
__device__ __forceinline__ u32 add3pack(u32 x, u32 y, u32 z) {
    float lo = blo(x) + blo(y) + blo(z);
    float hi = bhi(x) + bhi(y) + bhi(z);
    return (u32)f2b(lo) | ((u32)f2b(hi) << 16);
}

// ---------------------------------------------------------------------------
// K0+K2 merged: blocks 0..31 pre-swizzle weights into SWZ; remaining blocks
// compute segment bounds (batch_hyper sorted). Saves one launch.
// Panel(kt,nt): 16 n-rows x 40 u16 (pad 32->40). SWZ layout:
//   WB [0,5120) | V1B [5120,15360) | V2B [15360,20480)
// ---------------------------------------------------------------------------
__global__ __launch_bounds__(256) void prep_kernel(
    const float* __restrict__ Wg, const float* __restrict__ V1g,
    const float* __restrict__ V2g, u16* __restrict__ SWZ,
    const int* __restrict__ bh, int E, int G, int* __restrict__ seg_start)
{
    const int b = blockIdx.x, tid = threadIdx.x;
    if (b < 32) {
        int idx = b * 256 + tid;        // 0..8191
        int k = idx >> 6, n = idx & 63;
        int off = ((k >> 5) * 4 + (n >> 4)) * 640 + (n & 15) * 40 + ((k >> 3) & 3) * 8 + (k & 7);
        SWZ[5120 + off] = f2b(V1g[idx]);
        if (idx < 4096) {
            SWZ[off]         = f2b(Wg[idx]);
            SWZ[15360 + off] = f2b(V2g[idx]);
        }
    } else {
        int g = (b - 32) * 256 + tid;
        if (g > G) return;
        int lo = 0, hi = E;
        while (lo < hi) {
            int mid = (lo + hi) >> 1;
            if (bh[mid] < g) lo = mid + 1; else hi = mid;
        }
        seg_start[g] = lo;
    }
}

// ---------------------------------------------------------------------------
// K1: node MLP -> hb (bf16) [N,64].  float4 LDS reads (R9-verified).
// ---------------------------------------------------------------------------
__global__ __launch_bounds__(256) void node_mlp_kernel(
    const float* __restrict__ x, const float* __restrict__ u,
    const int* __restrict__ batch,
    const float* __restrict__ W1, const float* __restrict__ b1,
    const float* __restrict__ W2, const float* __restrict__ b2,
    const float* __restrict__ W3, const float* __restrict__ b3,
    u16* __restrict__ hb, int N)
{
    __shared__ float inbuf[4][10];
    __shared__ float h1[4][64];
    __shared__ float h2[4][64];
    const int tid = threadIdx.x;
    const int ni = tid >> 6, f = tid & 63;
    int node = blockIdx.x * 4 + ni;
    if (node >= N) node = N - 1;
    if (f < 6)       inbuf[ni][f] = x[node * 6 + f];
    else if (f < 10) inbuf[ni][f] = u[batch[node] * 4 + (f - 6)];
    __syncthreads();
    float acc = b1[f];
    #pragma unroll
    for (int k = 0; k < 10; ++k) acc = fmaf(inbuf[ni][k], W1[k * 64 + f], acc);
    h1[ni][f] = fmaxf(acc, 0.f);
    __syncthreads();
    acc = b2[f];
    #pragma unroll
    for (int k4 = 0; k4 < 16; ++k4) {
        float4 hv = *(const float4*)&h1[ni][k4 * 4];
        acc = fmaf(hv.x, W2[(k4 * 4 + 0) * 64 + f], acc);
        acc = fmaf(hv.y, W2[(k4 * 4 + 1) * 64 + f], acc);
        acc = fmaf(hv.z, W2[(k4 * 4 + 2) * 64 + f], acc);
        acc = fmaf(hv.w, W2[(k4 * 4 + 3) * 64 + f], acc);
    }
    h2[ni][f] = fmaxf(acc, 0.f);
    __syncthreads();
    acc = b3[f];
    #pragma unroll
    for (int k4 = 0; k4 < 16; ++k4) {
        float4 hv = *(const float4*)&h2[ni][k4 * 4];
        acc = fmaf(hv.x, W3[(k4 * 4 + 0) * 64 + f], acc);
        acc = fmaf(hv.y, W3[(k4 * 4 + 1) * 64 + f], acc);
        acc = fmaf(hv.z, W3[(k4 * 4 + 2) * 64 + f], acc);
        acc = fmaf(hv.w, W3[(k4 * 4 + 3) * 64 + f], acc);
    }
    hb[node * 64 + f] = f2b(acc);
}

// ---------------------------------------------------------------------------
// K3: gather + Xh write + softmax denominators + out[E..2E) writes.
// Standalone at max occupancy (R8 lesson). j unrolled x8 (R9-verified).
// exp of the bf16-ROUNDED sum (matches K4's A-frags exactly).
// ---------------------------------------------------------------------------
__global__ __launch_bounds__(256) void gather_stats_kernel(
    const u16* __restrict__ hb, const int* __restrict__ hidx,
    const int* __restrict__ seg_start,
    u16* __restrict__ Xh, float* __restrict__ Sinv,
    float* __restrict__ out, int E)
{
    __shared__ float ps[4][16][4];
    const int tid = threadIdx.x, lane = tid & 63, wid = tid >> 6;
    const int sub = lane >> 4, cl = lane & 15;
    const int g = blockIdx.x;
    const int e0 = seg_start[g], e1 = seg_start[g + 1];
    if (e1 <= e0) return;                       // uniform across block
    const int e1m1 = e1 - 1;
    const float gf = (float)g;

    for (int e = e0 + tid; e < e1; e += 256) out[E + e] = gf;   // coalesced

    float s0 = 0.f, s1 = 0.f, s2 = 0.f, s3 = 0.f;
    for (int e = e0 + wid * 4 + sub; e < e1; e += 128) {
        #pragma unroll
        for (int j = 0; j < 8; ++j) {
            int ee = e + j * 16;
            int ec = min(ee, e1m1);
            int i0 = hidx[ec], i1 = hidx[E + ec], i2 = hidx[2 * E + ec];
            uint2 A0 = *(const uint2*)(hb + (size_t)i0 * 64 + cl * 4);
            uint2 A1 = *(const uint2*)(hb + (size_t)i1 * 64 + cl * 4);
            uint2 A2 = *(const uint2*)(hb + (size_t)i2 * 64 + cl * 4);
            u32 wx = add3pack(A0.x, A1.x, A2.x);
            u32 wy = add3pack(A0.y, A1.y, A2.y);
            if (ee < e1) {
                uint2 W; W.x = wx; W.y = wy;
                *(uint2*)(Xh + (size_t)ee * 64 + cl * 4) = W;
                s0 += __expf(blo(wx)); s1 += __expf(bhi(wx));
                s2 += __expf(blo(wy)); s3 += __expf(bhi(wy));
            }
        }
    }
    s0 += __shfl_xor(s0, 16); s0 += __shfl_xor(s0, 32);
    s1 += __shfl_xor(s1, 16); s1 += __shfl_xor(s1, 32);
    s2 += __shfl_xor(s2, 16); s2 += __shfl_xor(s2, 32);
    s3 += __shfl_xor(s3, 16); s3 += __shfl_xor(s3, 32);
    if (lane < 16) {
        ps[wid][cl][0] = s0; ps[wid][cl][1] = s1;
        ps[wid][cl][2] = s2; ps[wid][cl][3] = s3;
    }
    __syncthreads();
    if (tid < 64) {
        int c4 = tid >> 2, cc = tid & 3;
        float S = ps[0][c4][cc] + ps[1][c4][cc] + ps[2][c4][cc] + ps[3][c4][cc];
        Sinv[g * 64 + tid] = 1.f / S;
    }
}

// ---------------------------------------------------------------------------
// K4: MFMA chain, TWO TILES PER WAVE-ITERATION sharing B-fragment reads.
// Wave processes pair (t, t+4), stride 8: every B ds_read_b128 feeds 2
// MFMAs (DS/tile -31%) and two independent chains interleave (latency /2).
// XT region reused sequentially by the pair (tile1's x/o reads complete
// before tile2's overwrite; per-wave in-order DS). Phantom 2nd tile at
// segment tail: loads clamped, stores guarded.
// Locked config: 256-thr blocks, __launch_bounds__(256,3) (R9: 512-thr =
// 64-VGPR spill mode), all weights in LDS (R5), Xh streamed w/ prefetch
// (R7). Reg peak audit ~152 < ~168 budget; spill tripwire = FETCH>450MB.
// LDS: 40960(SW) + 9216(XT) = 50176 B -> 3 blocks/CU.
// ---------------------------------------------------------------------------
__global__ __launch_bounds__(256, 3) void mfma_seg_kernel(
    const u16* __restrict__ Xh, const int* __restrict__ seg_start,
    const u16* __restrict__ SWZ, const float* __restrict__ Sinv,
    const float* __restrict__ c1g, const float* __restrict__ c2g,
    const float* __restrict__ V3g, const float* __restrict__ c3g,
    float* __restrict__ out, int E)
{
    __shared__ u16 SW[20480];          // WB[0,5120)+V1B[5120,15360)+V2B[15360,20480)
    __shared__ u16 XT_all[4][16 * 72]; // per-wave transpose tile (shared by pair)

    const int tid = threadIdx.x, lane = tid & 63, wid = tid >> 6;
    const int nl = lane & 15, rq = lane >> 4;
    const int g = blockIdx.x;
    const int e0 = seg_start[g], e1 = seg_start[g + 1];
    const int L = e1 - e0;
    if (L <= 0) return;
    const int e1m1 = e1 - 1;

    {   // stage pre-swizzled W+V1+V2: 40960 B = 2560 uint4
        const uint4* src = (const uint4*)SWZ;
        uint4* dst = (uint4*)SW;
        for (int i = tid; i < 2560; i += 256) dst[i] = src[i];
    }
    __syncthreads();
    const u16* WB  = SW;
    const u16* V1B = SW + 5120;
    const u16* V2B = SW + 15360;

    // identity B-frags for X C-layout redistribution (exact in bf16)
    bf16x8 I0, I1;
    #pragma unroll
    for (int j = 0; j < 8; ++j) {
        I0[j] = (rq * 8 + j == nl)      ? (short)0x3F80 : (short)0;
        I1[j] = (rq * 8 + j == nl + 16) ? (short)0x3F80 : (short)0;
    }

    float dinvv[4], c1v[4], c2v[4], v3v[4];
    #pragma unroll
    for (int nt = 0; nt < 4; ++nt) {
        int col = nt * 16 + nl;
        dinvv[nt] = Sinv[g * 64 + col];
        c1v[nt]   = c1g[col];
        c2v[nt]   = c2g[col];
        v3v[nt]   = V3g[col];
    }
    const float c3s = c3g[0];
    u16* XT = XT_all[wid];
    const f32x4 zf = {0.f, 0.f, 0.f, 0.f};

    // clamped a-frag load for tile tt (safe for any tt)
    auto loadA = [&](int tt, bf16x8& A0, bf16x8& A1) {
        const u16* xp = Xh + (size_t)min(e0 + tt * 16 + nl, e1m1) * 64 + rq * 8;
        A0 = *(const bf16x8*)(xp);
        A1 = *(const bf16x8*)(xp + 32);
    };

    int t = wid;
    bf16x8 p0 = {}, p1 = {};
    if (t * 16 < L) loadA(t, p0, p1);

    for (; t * 16 < L; t += 8) {
        const int eB1 = e0 + t * 16;
        const int eB2 = eB1 + 64;                 // tile t+4 (may be phantom)

        bf16x8 a0 = p0, a1 = p1;                  // tile 1 (prefetched)
        bf16x8 a2, a3;
        loadA(t + 4, a2, a3);                     // tile 2 (clamped)
        if ((t + 8) * 16 < L) loadA(t + 8, p0, p1);  // prefetch next pair's 1st

        // xv in C-layout via identity MFMA, both tiles
        f32x4 xc1[4], xc2[4];
        xc1[0] = MFMA16(a0, I0, zf, 0, 0, 0);
        xc1[1] = MFMA16(a0, I1, zf, 0, 0, 0);
        xc1[2] = MFMA16(a1, I0, zf, 0, 0, 0);
        xc1[3] = MFMA16(a1, I1, zf, 0, 0, 0);
        xc2[0] = MFMA16(a2, I0, zf, 0, 0, 0);
        xc2[1] = MFMA16(a2, I1, zf, 0, 0, 0);
        xc2[2] = MFMA16(a3, I0, zf, 0, 0, 0);
        xc2[3] = MFMA16(a3, I1, zf, 0, 0, 0);

        // ---- layer W (B-frags shared) ----
        f32x4 acc1[4] = {zf, zf, zf, zf}, acc2t[4] = {zf, zf, zf, zf};
        #pragma unroll
        for (int nt = 0; nt < 4; ++nt) {
            bf16x8 b0 = *(const bf16x8*)(WB + (0 * 4 + nt) * 640 + nl * 40 + rq * 8);
            acc1[nt]  = MFMA16(a0, b0, acc1[nt], 0, 0, 0);
            acc2t[nt] = MFMA16(a2, b0, acc2t[nt], 0, 0, 0);
            bf16x8 b1 = *(const bf16x8*)(WB + (1 * 4 + nt) * 640 + nl * 40 + rq * 8);
            acc1[nt]  = MFMA16(a1, b1, acc1[nt], 0, 0, 0);
            acc2t[nt] = MFMA16(a3, b1, acc2t[nt], 0, 0, 0);
        }
        // Xhat epilogue tile1 -> XT, read x-frags; then tile2 (region reuse)
        #pragma unroll
        for (int nt = 0; nt < 4; ++nt) {
            #pragma unroll
            for (int r = 0; r < 4; ++r) {
                float coef = __expf(xc1[nt][r]) * dinvv[nt];
                XT[(rq * 4 + r) * 72 + nt * 16 + nl] =
                    f2b(coef * fmaxf(acc1[nt][r], 0.f));
            }
        }
        bf16x8 x2a = *(const bf16x8*)(XT + nl * 72 + rq * 8);
        bf16x8 x3a = *(const bf16x8*)(XT + nl * 72 + 32 + rq * 8);
        #pragma unroll
        for (int nt = 0; nt < 4; ++nt) {
            #pragma unroll
            for (int r = 0; r < 4; ++r) {
                float coef = __expf(xc2[nt][r]) * dinvv[nt];
                XT[(rq * 4 + r) * 72 + nt * 16 + nl] =
                    f2b(coef * fmaxf(acc2t[nt][r], 0.f));
            }
        }
        bf16x8 x2b = *(const bf16x8*)(XT + nl * 72 + rq * 8);
        bf16x8 x3b = *(const bf16x8*)(XT + nl * 72 + 32 + rq * 8);

        // ---- layer V1 (B-frags shared) ----
        f32x4 va[4], vb[4];
        #pragma unroll
        for (int nt = 0; nt < 4; ++nt) {
            va[nt][0] = c1v[nt]; va[nt][1] = c1v[nt];
            va[nt][2] = c1v[nt]; va[nt][3] = c1v[nt];
            vb[nt] = va[nt];
        }
        #pragma unroll
        for (int nt = 0; nt < 4; ++nt) {
            bf16x8 b0 = *(const bf16x8*)(V1B + (0 * 4 + nt) * 640 + nl * 40 + rq * 8);
            va[nt] = MFMA16(a0, b0, va[nt], 0, 0, 0);
            vb[nt] = MFMA16(a2, b0, vb[nt], 0, 0, 0);
            bf16x8 b1 = *(const bf16x8*)(V1B + (1 * 4 + nt) * 640 + nl * 40 + rq * 8);
            va[nt] = MFMA16(a1, b1, va[nt], 0, 0, 0);
            vb[nt] = MFMA16(a3, b1, vb[nt], 0, 0, 0);
        }
        #pragma unroll
        for (int nt = 0; nt < 4; ++nt) {
            bf16x8 b2 = *(const bf16x8*)(V1B + (2 * 4 + nt) * 640 + nl * 40 + rq * 8);
            va[nt] = MFMA16(x2a, b2, va[nt], 0, 0, 0);
            vb[nt] = MFMA16(x2b, b2, vb[nt], 0, 0, 0);
            bf16x8 b3 = *(const bf16x8*)(V1B + (3 * 4 + nt) * 640 + nl * 40 + rq * 8);
            va[nt] = MFMA16(x3a, b3, va[nt], 0, 0, 0);
            vb[nt] = MFMA16(x3b, b3, vb[nt], 0, 0, 0);
        }
        // O1 epilogue tile1 -> XT, read o-frags; then tile2
        #pragma unroll
        for (int nt = 0; nt < 4; ++nt) {
            #pragma unroll
            for (int r = 0; r < 4; ++r)
                XT[(rq * 4 + r) * 72 + nt * 16 + nl] = f2b(fmaxf(va[nt][r], 0.f));
        }
        bf16x8 o0a = *(const bf16x8*)(XT + nl * 72 + rq * 8);
        bf16x8 o1a = *(const bf16x8*)(XT + nl * 72 + 32 + rq * 8);
        #pragma unroll
        for (int nt = 0; nt < 4; ++nt) {
            #pragma unroll
            for (int r = 0; r < 4; ++r)
                XT[(rq * 4 + r) * 72 + nt * 16 + nl] = f2b(fmaxf(vb[nt][r], 0.f));
        }
        bf16x8 o0b = *(const bf16x8*)(XT + nl * 72 + rq * 8);
        bf16x8 o1b = *(const bf16x8*)(XT + nl * 72 + 32 + rq * 8);

        // ---- layer V2 (B-frags shared) ----
        f32x4 wa[4], wb2[4];
        #pragma unroll
        for (int nt = 0; nt < 4; ++nt) {
            wa[nt][0] = c2v[nt]; wa[nt][1] = c2v[nt];
            wa[nt][2] = c2v[nt]; wa[nt][3] = c2v[nt];
            wb2[nt] = wa[nt];
        }
        #pragma unroll
        for (int nt = 0; nt < 4; ++nt) {
            bf16x8 b0 = *(const bf16x8*)(V2B + (0 * 4 + nt) * 640 + nl * 40 + rq * 8);
            wa[nt]  = MFMA16(o0a, b0, wa[nt], 0, 0, 0);
            wb2[nt] = MFMA16(o0b, b0, wb2[nt], 0, 0, 0);
            bf16x8 b1 = *(const bf16x8*)(V2B + (1 * 4 + nt) * 640 + nl * 40 + rq * 8);
            wa[nt]  = MFMA16(o1a, b1, wa[nt], 0, 0, 0);
            wb2[nt] = MFMA16(o1b, b1, wb2[nt], 0, 0, 0);
        }

        // ---- V3 + sigmoid, both tiles ----
        float sra[4], srb[4];
        #pragma unroll
        for (int r = 0; r < 4; ++r) {
            float u1 = 0.f, u2 = 0.f;
            #pragma unroll
            for (int nt = 0; nt < 4; ++nt) {
                u1 = fmaf(fmaxf(wa[nt][r],  0.f), v3v[nt], u1);
                u2 = fmaf(fmaxf(wb2[nt][r], 0.f), v3v[nt], u2);
            }
            u1 += __shfl_xor(u1, 1); u2 += __shfl_xor(u2, 1);
            u1 += __shfl_xor(u1, 2); u2 += __shfl_xor(u2, 2);
            u1 += __shfl_xor(u1, 4); u2 += __shfl_xor(u2, 4);
            u1 += __shfl_xor(u1, 8); u2 += __shfl_xor(u2, 8);
            sra[r] = u1; srb[r] = u2;
        }
        if (nl == 0) {
            #pragma unroll
            for (int r = 0; r < 4; ++r) {
                int ea = eB1 + rq * 4 + r;
                if (ea < e1) out[ea] = 1.f / (1.f + __expf(-(sra[r] + c3s)));
                int eb = eB2 + rq * 4 + r;
                if (eb < e1) out[eb] = 1.f / (1.f + __expf(-(srb[r] + c3s)));
            }
        }
    }
}

// ---------------------------------------------------------------------------
extern "C" void kernel_launch(void* const* d_in, const int* in_sizes, int n_in,
                              void* d_out, int out_size, void* d_ws, size_t ws_size,
                              hipStream_t stream) {
    const float* x     = (const float*)d_in[0];
    const float* u     = (const float*)d_in[1];
    const int*   batch = (const int*)  d_in[2];
    const int*   hidx  = (const int*)  d_in[3];
    const int*   bh    = (const int*)  d_in[4];
    const float* W1 = (const float*)d_in[6];
    const float* b1 = (const float*)d_in[7];
    const float* W2 = (const float*)d_in[8];
    const float* b2 = (const float*)d_in[9];
    const float* W3 = (const float*)d_in[10];
    const float* b3 = (const float*)d_in[11];
    const float* Wg = (const float*)d_in[12];
    const float* V1 = (const float*)d_in[13];
    const float* c1 = (const float*)d_in[14];
    const float* V2 = (const float*)d_in[15];
    const float* c2 = (const float*)d_in[16];
    const float* V3 = (const float*)d_in[17];
    const float* c3 = (const float*)d_in[18];

    const int N = in_sizes[0] / 6;
    const int G = in_sizes[1] / 4;
    const int E = in_sizes[4];

    // ws layout
    char* ws = (char*)d_ws;
    size_t off = 0;
    u16* hb = (u16*)(ws + off);            off += (size_t)N * 64 * 2;
    int* seg_start = (int*)(ws + off);     off += ((size_t)G + 1) * 4;
    off = (off + 255) & ~(size_t)255;
    u16* SWZ = (u16*)(ws + off);           off += 20480 * 2;
    float* Sinv = (float*)(ws + off);      off += (size_t)G * 64 * 4;
    off = (off + 255) & ~(size_t)255;
    u16* Xh = (u16*)(ws + off);            off += (size_t)E * 64 * 2;
    float* out = (float*)d_out;

    const int prep_blocks = 32 + (G + 256) / 256;
    prep_kernel<<<prep_blocks, 256, 0, stream>>>(Wg, V1, V2, SWZ, bh, E, G, seg_start);
    node_mlp_kernel<<<(N + 3) / 4, 256, 0, stream>>>(
        x, u, batch, W1, b1, W2, b2, W3, b3, hb, N);
    gather_stats_kernel<<<G, 256, 0, stream>>>(hb, hidx, seg_start, Xh, Sinv, out, E);
    mfma_seg_kernel<<<G, 256, 0, stream>>>(
        Xh, seg_start, SWZ, Sinv, c1, c2, V3, c3, out, E);
}

// Round 12
// 270.349 us; speedup vs baseline: 1.9099x; 1.0362x over previous
//
#include <hip/hip_runtime.h>
#include <math.h>

typedef short bf16x8 __attribute__((ext_vector_type(8)));
typedef float f32x4  __attribute__((ext_vector_type(4)));
typedef unsigned short u16;
typedef unsigned int   u32;

#define MFMA16 __builtin_amdgcn_mfma_f32_16x16x32_bf16

__device__ __forceinline__ u16 f2b(float x) {   // fp32 -> bf16 RNE
    union { float f; unsigned u; } v; v.f = x;
    unsigned r = v.u + 0x7fffu + ((v.u >> 16) & 1u);
    return (u16)(r >> 16);
}
// round-half-up bf16 (2 VALU vs 4; <=0.5ulp; used ONLY for K4's Xhat/O1
// intermediate quantization -- Xh/h/weights stay RNE for exp consistency)
__device__ __forceinline__ u16 f2bu(float x) {
    union { float f; unsigned u; } v; v.f = x;
    return (u16)((v.u + 0x8000u) >> 16);
}
__device__ __forceinline__ float b2f(u16 h) {
    union { unsigned u; float f; } v; v.u = ((unsigned)h) << 16;
    return v.f;
}
__device__ __forceinline__ float blo(u32 w) {
    union { u32 u; float f; } v; v.u = w << 16; return v.f;
}
__device__ __forceinline__ float bhi(u32 w) {
    union { u32 u; float f; } v; v.u = w & 0xffff0000u; return v.f;
}
// sum 3 packed bf16 pairs in fp32 (order i0+i1+i2), repack bf16 RNE
__device__ __forceinline__ u32 add3pack(u32 x, u32 y, u32 z) {
    float lo = blo(x) + blo(y) + blo(z);
    float hi = bhi(x) + bhi(y) + bhi(z);
    return (u32)f2b(lo) | ((u32)f2b(hi) << 16);
}

// ---------------------------------------------------------------------------
// K0+K2 merged: blocks 0..31 pre-swizzle weights into SWZ; remaining blocks
// compute segment bounds (batch_hyper sorted).
// Panel(kt,nt): 16 n-rows x 40 u16. SWZ: WB[0,5120)|V1B[5120,15360)|V2B[15360,20480)
// ---------------------------------------------------------------------------
__global__ __launch_bounds__(256) void prep_kernel(
    const float* __restrict__ Wg, const float* __restrict__ V1g,
    const float* __restrict__ V2g, u16* __restrict__ SWZ,
    const int* __restrict__ bh, int E, int G, int* __restrict__ seg_start)
{
    const int b = blockIdx.x, tid = threadIdx.x;
    if (b < 32) {
        int idx = b * 256 + tid;        // 0..8191
        int k = idx >> 6, n = idx & 63;
        int off = ((k >> 5) * 4 + (n >> 4)) * 640 + (n & 15) * 40 + ((k >> 3) & 3) * 8 + (k & 7);
        SWZ[5120 + off] = f2b(V1g[idx]);
        if (idx < 4096) {
            SWZ[off]         = f2b(Wg[idx]);
            SWZ[15360 + off] = f2b(V2g[idx]);
        }
    } else {
        int g = (b - 32) * 256 + tid;
        if (g > G) return;
        int lo = 0, hi = E;
        while (lo < hi) {
            int mid = (lo + hi) >> 1;
            if (bh[mid] < g) lo = mid + 1; else hi = mid;
        }
        seg_start[g] = lo;
    }
}

// ---------------------------------------------------------------------------
// K1: node MLP -> hb (bf16) [N,64]. 16 nodes/block, 4 nodes/thread:
// W2/W3 scalar loads amortized 4x (128->32 VMEM per node). Per-node fma
// order unchanged (k ascending) -> h bit-identical to R10.
// ---------------------------------------------------------------------------
__global__ __launch_bounds__(256) void node_mlp_kernel(
    const float* __restrict__ x, const float* __restrict__ u,
    const int* __restrict__ batch,
    const float* __restrict__ W1, const float* __restrict__ b1,
    const float* __restrict__ W2, const float* __restrict__ b2,
    const float* __restrict__ W3, const float* __restrict__ b3,
    u16* __restrict__ hb, int N)
{
    __shared__ float inbuf[16][10];
    __shared__ float h1[16][64];
    __shared__ float h2[16][64];
    const int tid = threadIdx.x;
    const int ni = tid >> 6, f = tid & 63;
    const int base = blockIdx.x * 16;
    int nodes[4];
    #pragma unroll
    for (int s = 0; s < 4; ++s) {
        nodes[s] = min(base + s * 4 + ni, N - 1);
        if (f < 6)       inbuf[s * 4 + ni][f] = x[nodes[s] * 6 + f];
        else if (f < 10) inbuf[s * 4 + ni][f] = u[batch[nodes[s]] * 4 + (f - 6)];
    }
    __syncthreads();
    float acc[4];
    #pragma unroll
    for (int s = 0; s < 4; ++s) acc[s] = b1[f];
    #pragma unroll
    for (int k = 0; k < 10; ++k) {
        float w = W1[k * 64 + f];
        #pragma unroll
        for (int s = 0; s < 4; ++s) acc[s] = fmaf(inbuf[s * 4 + ni][k], w, acc[s]);
    }
    #pragma unroll
    for (int s = 0; s < 4; ++s) h1[s * 4 + ni][f] = fmaxf(acc[s], 0.f);
    __syncthreads();
    #pragma unroll
    for (int s = 0; s < 4; ++s) acc[s] = b2[f];
    #pragma unroll
    for (int k4 = 0; k4 < 16; ++k4) {
        float w0 = W2[(k4 * 4 + 0) * 64 + f];
        float w1 = W2[(k4 * 4 + 1) * 64 + f];
        float w2 = W2[(k4 * 4 + 2) * 64 + f];
        float w3 = W2[(k4 * 4 + 3) * 64 + f];
        #pragma unroll
        for (int s = 0; s < 4; ++s) {
            float4 hv = *(const float4*)&h1[s * 4 + ni][k4 * 4];
            acc[s] = fmaf(hv.x, w0, acc[s]);
            acc[s] = fmaf(hv.y, w1, acc[s]);
            acc[s] = fmaf(hv.z, w2, acc[s]);
            acc[s] = fmaf(hv.w, w3, acc[s]);
        }
    }
    #pragma unroll
    for (int s = 0; s < 4; ++s) h2[s * 4 + ni][f] = fmaxf(acc[s], 0.f);
    __syncthreads();
    #pragma unroll
    for (int s = 0; s < 4; ++s) acc[s] = b3[f];
    #pragma unroll
    for (int k4 = 0; k4 < 16; ++k4) {
        float w0 = W3[(k4 * 4 + 0) * 64 + f];
        float w1 = W3[(k4 * 4 + 1) * 64 + f];
        float w2 = W3[(k4 * 4 + 2) * 64 + f];
        float w3 = W3[(k4 * 4 + 3) * 64 + f];
        #pragma unroll
        for (int s = 0; s < 4; ++s) {
            float4 hv = *(const float4*)&h2[s * 4 + ni][k4 * 4];
            acc[s] = fmaf(hv.x, w0, acc[s]);
            acc[s] = fmaf(hv.y, w1, acc[s]);
            acc[s] = fmaf(hv.z, w2, acc[s]);
            acc[s] = fmaf(hv.w, w3, acc[s]);
        }
    }
    #pragma unroll
    for (int s = 0; s < 4; ++s) hb[nodes[s] * 64 + f] = f2b(acc[s]);
}

// ---------------------------------------------------------------------------
// K3: gather + Xh write + softmax denominators + out[E..2E) writes.
// uint4 gathers (16B/lane): 8 lanes cover a 128B row, sub=lane>>3 picks the
// edge (8 edges/wave-group), unroll 4 -> 12 uint4 + 12 idx loads in flight,
// HALF the VMEM instructions of R10 for the same data. Xh stores 16B
// coalesced. exp of the RNE-rounded sum (matches K4's A-frags exactly).
// Standalone at high occupancy (R8 lesson: do NOT fuse with MFMA phase).
// ---------------------------------------------------------------------------
__global__ __launch_bounds__(256) void gather_stats_kernel(
    const u16* __restrict__ hb, const int* __restrict__ hidx,
    const int* __restrict__ seg_start,
    u16* __restrict__ Xh, float* __restrict__ Sinv,
    float* __restrict__ out, int E)
{
    __shared__ float ps[4][8][8];
    const int tid = threadIdx.x, lane = tid & 63, wid = tid >> 6;
    const int sub = lane >> 3, cl = lane & 7;    // sub: edge, cl: col-group of 8
    const int g = blockIdx.x;
    const int e0 = seg_start[g], e1 = seg_start[g + 1];
    if (e1 <= e0) return;                        // uniform across block
    const int e1m1 = e1 - 1;
    const float gf = (float)g;

    for (int e = e0 + tid; e < e1; e += 256) out[E + e] = gf;   // coalesced

    float s[8] = {0.f, 0.f, 0.f, 0.f, 0.f, 0.f, 0.f, 0.f};
    for (int e = e0 + wid * 8 + sub; e < e1; e += 128) {
        #pragma unroll
        for (int j = 0; j < 4; ++j) {
            int ee = e + j * 32;
            int ec = min(ee, e1m1);
            int i0 = hidx[ec], i1 = hidx[E + ec], i2 = hidx[2 * E + ec];
            uint4 A0 = *(const uint4*)(hb + (size_t)i0 * 64 + cl * 8);
            uint4 A1 = *(const uint4*)(hb + (size_t)i1 * 64 + cl * 8);
            uint4 A2 = *(const uint4*)(hb + (size_t)i2 * 64 + cl * 8);
            u32 w0 = add3pack(A0.x, A1.x, A2.x);
            u32 w1 = add3pack(A0.y, A1.y, A2.y);
            u32 w2 = add3pack(A0.z, A1.z, A2.z);
            u32 w3 = add3pack(A0.w, A1.w, A2.w);
            if (ee < e1) {
                uint4 W; W.x = w0; W.y = w1; W.z = w2; W.w = w3;
                *(uint4*)(Xh + (size_t)ee * 64 + cl * 8) = W;
                s[0] += __expf(blo(w0)); s[1] += __expf(bhi(w0));
                s[2] += __expf(blo(w1)); s[3] += __expf(bhi(w1));
                s[4] += __expf(blo(w2)); s[5] += __expf(bhi(w2));
                s[6] += __expf(blo(w3)); s[7] += __expf(bhi(w3));
            }
        }
    }
    // reduce over sub (lane bits 3,4,5), then across waves via LDS
    #pragma unroll
    for (int k = 0; k < 8; ++k) {
        s[k] += __shfl_xor(s[k], 8);
        s[k] += __shfl_xor(s[k], 16);
        s[k] += __shfl_xor(s[k], 32);
    }
    if (lane < 8) {
        #pragma unroll
        for (int k = 0; k < 8; ++k) ps[wid][lane][k] = s[k];
    }
    __syncthreads();
    if (tid < 64) {
        int c8 = tid >> 3, cc = tid & 7;
        float S = ps[0][c8][cc] + ps[1][c8][cc] + ps[2][c8][cc] + ps[3][c8][cc];
        Sinv[g * 64 + tid] = 1.f / S;
    }
}

// ---------------------------------------------------------------------------
// K4: paired-tile MFMA chain (R11-verified structure, 2 tiles/wave-iter
// sharing B-frag reads). R12 deltas only:
//  - XT stride 72 -> 76 u16: b128 reads were 8-way bank-conflicted
//    (bank=4(nl+rq)%32), writes 4-way; stride 76 makes both ~2-way (free).
//  - epilogue converts f2b(RNE,4 instr) -> f2bu(half-up,2 instr): VALU was
//    the binding pipe (62% busy, ~256 instr/pair-iter in converts).
// Locked: 256-thr blocks + (256,3) (R9), weights in LDS (R5), Xh streamed
// w/ prefetch (R7). LDS: 40960(SW) + 9728(XT) = 50688 B -> 3 blocks/CU.
// ---------------------------------------------------------------------------
__global__ __launch_bounds__(256, 3) void mfma_seg_kernel(
    const u16* __restrict__ Xh, const int* __restrict__ seg_start,
    const u16* __restrict__ SWZ, const float* __restrict__ Sinv,
    const float* __restrict__ c1g, const float* __restrict__ c2g,
    const float* __restrict__ V3g, const float* __restrict__ c3g,
    float* __restrict__ out, int E)
{
    __shared__ u16 SW[20480];          // WB[0,5120)+V1B[5120,15360)+V2B[15360,20480)
    __shared__ u16 XT_all[4][16 * 76]; // per-wave transpose tile, stride 76

    const int tid = threadIdx.x, lane = tid & 63, wid = tid >> 6;
    const int nl = lane & 15, rq = lane >> 4;
    const int g = blockIdx.x;
    const int e0 = seg_start[g], e1 = seg_start[g + 1];
    const int L = e1 - e0;
    if (L <= 0) return;
    const int e1m1 = e1 - 1;

    {   // stage pre-swizzled W+V1+V2: 40960 B = 2560 uint4
        const uint4* src = (const uint4*)SWZ;
        uint4* dst = (uint4*)SW;
        for (int i = tid; i < 2560; i += 256) dst[i] = src[i];
    }
    __syncthreads();
    const u16* WB  = SW;
    const u16* V1B = SW + 5120;
    const u16* V2B = SW + 15360;

    // identity B-frags for X C-layout redistribution (exact in bf16)
    bf16x8 I0, I1;
    #pragma unroll
    for (int j = 0; j < 8; ++j) {
        I0[j] = (rq * 8 + j == nl)      ? (short)0x3F80 : (short)0;
        I1[j] = (rq * 8 + j == nl + 16) ? (short)0x3F80 : (short)0;
    }

    float dinvv[4], c1v[4], c2v[4], v3v[4];
    #pragma unroll
    for (int nt = 0; nt < 4; ++nt) {
        int col = nt * 16 + nl;
        dinvv[nt] = Sinv[g * 64 + col];
        c1v[nt]   = c1g[col];
        c2v[nt]   = c2g[col];
        v3v[nt]   = V3g[col];
    }
    const float c3s = c3g[0];
    u16* XT = XT_all[wid];
    const f32x4 zf = {0.f, 0.f, 0.f, 0.f};

    auto loadA = [&](int tt, bf16x8& A0, bf16x8& A1) {
        const u16* xp = Xh + (size_t)min(e0 + tt * 16 + nl, e1m1) * 64 + rq * 8;
        A0 = *(const bf16x8*)(xp);
        A1 = *(const bf16x8*)(xp + 32);
    };

    int t = wid;
    bf16x8 p0 = {}, p1 = {};
    if (t * 16 < L) loadA(t, p0, p1);

    for (; t * 16 < L; t += 8) {
        const int eB1 = e0 + t * 16;
        const int eB2 = eB1 + 64;                 // tile t+4 (may be phantom)

        bf16x8 a0 = p0, a1 = p1;                  // tile 1 (prefetched)
        bf16x8 a2, a3;
        loadA(t + 4, a2, a3);                     // tile 2 (clamped)
        if ((t + 8) * 16 < L) loadA(t + 8, p0, p1);  // prefetch next pair's 1st

        // xv in C-layout via identity MFMA, both tiles
        f32x4 xc1[4], xc2[4];
        xc1[0] = MFMA16(a0, I0, zf, 0, 0, 0);
        xc1[1] = MFMA16(a0, I1, zf, 0, 0, 0);
        xc1[2] = MFMA16(a1, I0, zf, 0, 0, 0);
        xc1[3] = MFMA16(a1, I1, zf, 0, 0, 0);
        xc2[0] = MFMA16(a2, I0, zf, 0, 0, 0);
        xc2[1] = MFMA16(a2, I1, zf, 0, 0, 0);
        xc2[2] = MFMA16(a3, I0, zf, 0, 0, 0);
        xc2[3] = MFMA16(a3, I1, zf, 0, 0, 0);

        // ---- layer W (B-frags shared) ----
        f32x4 acc1[4] = {zf, zf, zf, zf}, acc2t[4] = {zf, zf, zf, zf};
        #pragma unroll
        for (int nt = 0; nt < 4; ++nt) {
            bf16x8 b0 = *(const bf16x8*)(WB + (0 * 4 + nt) * 640 + nl * 40 + rq * 8);
            acc1[nt]  = MFMA16(a0, b0, acc1[nt], 0, 0, 0);
            acc2t[nt] = MFMA16(a2, b0, acc2t[nt], 0, 0, 0);
            bf16x8 b1 = *(const bf16x8*)(WB + (1 * 4 + nt) * 640 + nl * 40 + rq * 8);
            acc1[nt]  = MFMA16(a1, b1, acc1[nt], 0, 0, 0);
            acc2t[nt] = MFMA16(a3, b1, acc2t[nt], 0, 0, 0);
        }
        // Xhat epilogue tile1 -> XT, read x-frags; then tile2 (region reuse)
        #pragma unroll
        for (int nt = 0; nt < 4; ++nt) {
            #pragma unroll
            for (int r = 0; r < 4; ++r) {
                float coef = __expf(xc1[nt][r]) * dinvv[nt];
                XT[(rq * 4 + r) * 76 + nt * 16 + nl] =
                    f2bu(coef * fmaxf(acc1[nt][r], 0.f));
            }
        }
        bf16x8 x2a = *(const bf16x8*)(XT + nl * 76 + rq * 8);
        bf16x8 x3a = *(const bf16x8*)(XT + nl * 76 + 32 + rq * 8);
        #pragma unroll
        for (int nt = 0; nt < 4; ++nt) {
            #pragma unroll
            for (int r = 0; r < 4; ++r) {
                float coef = __expf(xc2[nt][r]) * dinvv[nt];
                XT[(rq * 4 + r) * 76 + nt * 16 + nl] =
                    f2bu(coef * fmaxf(acc2t[nt][r], 0.f));
            }
        }
        bf16x8 x2b = *(const bf16x8*)(XT + nl * 76 + rq * 8);
        bf16x8 x3b = *(const bf16x8*)(XT + nl * 76 + 32 + rq * 8);

        // ---- layer V1 (B-frags shared) ----
        f32x4 va[4], vb[4];
        #pragma unroll
        for (int nt = 0; nt < 4; ++nt) {
            va[nt][0] = c1v[nt]; va[nt][1] = c1v[nt];
            va[nt][2] = c1v[nt]; va[nt][3] = c1v[nt];
            vb[nt] = va[nt];
        }
        #pragma unroll
        for (int nt = 0; nt < 4; ++nt) {
            bf16x8 b0 = *(const bf16x8*)(V1B + (0 * 4 + nt) * 640 + nl * 40 + rq * 8);
            va[nt] = MFMA16(a0, b0, va[nt], 0, 0, 0);
            vb[nt] = MFMA16(a2, b0, vb[nt], 0, 0, 0);
            bf16x8 b1 = *(const bf16x8*)(V1B + (1 * 4 + nt) * 640 + nl * 40 + rq * 8);
            va[nt] = MFMA16(a1, b1, va[nt], 0, 0, 0);
            vb[nt] = MFMA16(a3, b1, vb[nt], 0, 0, 0);
        }
        #pragma unroll
        for (int nt = 0; nt < 4; ++nt) {
            bf16x8 b2 = *(const bf16x8*)(V1B + (2 * 4 + nt) * 640 + nl * 40 + rq * 8);
            va[nt] = MFMA16(x2a, b2, va[nt], 0, 0, 0);
            vb[nt] = MFMA16(x2b, b2, vb[nt], 0, 0, 0);
            bf16x8 b3 = *(const bf16x8*)(V1B + (3 * 4 + nt) * 640 + nl * 40 + rq * 8);
            va[nt] = MFMA16(x3a, b3, va[nt], 0, 0, 0);
            vb[nt] = MFMA16(x3b, b3, vb[nt], 0, 0, 0);
        }
        // O1 epilogue tile1 -> XT, read o-frags; then tile2
        #pragma unroll
        for (int nt = 0; nt < 4; ++nt) {
            #pragma unroll
            for (int r = 0; r < 4; ++r)
                XT[(rq * 4 + r) * 76 + nt * 16 + nl] = f2bu(fmaxf(va[nt][r], 0.f));
        }
        bf16x8 o0a = *(const bf16x8*)(XT + nl * 76 + rq * 8);
        bf16x8 o1a = *(const bf16x8*)(XT + nl * 76 + 32 + rq * 8);
        #pragma unroll
        for (int nt = 0; nt < 4; ++nt) {
            #pragma unroll
            for (int r = 0; r < 4; ++r)
                XT[(rq * 4 + r) * 76 + nt * 16 + nl] = f2bu(fmaxf(vb[nt][r], 0.f));
        }
        bf16x8 o0b = *(const bf16x8*)(XT + nl * 76 + rq * 8);
        bf16x8 o1b = *(const bf16x8*)(XT + nl * 76 + 32 + rq * 8);

        // ---- layer V2 (B-frags shared) ----
        f32x4 wa[4], wb2[4];
        #pragma unroll
        for (int nt = 0; nt < 4; ++nt) {
            wa[nt][0] = c2v[nt]; wa[nt][1] = c2v[nt];
            wa[nt][2] = c2v[nt]; wa[nt][3] = c2v[nt];
            wb2[nt] = wa[nt];
        }
        #pragma unroll
        for (int nt = 0; nt < 4; ++nt) {
            bf16x8 b0 = *(const bf16x8*)(V2B + (0 * 4 + nt) * 640 + nl * 40 + rq * 8);
            wa[nt]  = MFMA16(o0a, b0, wa[nt], 0, 0, 0);
            wb2[nt] = MFMA16(o0b, b0, wb2[nt], 0, 0, 0);
            bf16x8 b1 = *(const bf16x8*)(V2B + (1 * 4 + nt) * 640 + nl * 40 + rq * 8);
            wa[nt]  = MFMA16(o1a, b1, wa[nt], 0, 0, 0);
            wb2[nt] = MFMA16(o1b, b1, wb2[nt], 0, 0, 0);
        }

        // ---- V3 + sigmoid, both tiles ----
        float sra[4], srb[4];
        #pragma unroll
        for (int r = 0; r < 4; ++r) {
            float u1 = 0.f, u2 = 0.f;
            #pragma unroll
            for (int nt = 0; nt < 4; ++nt) {
                u1 = fmaf(fmaxf(wa[nt][r],  0.f), v3v[nt], u1);
                u2 = fmaf(fmaxf(wb2[nt][r], 0.f), v3v[nt], u2);
            }
            u1 += __shfl_xor(u1, 1); u2 += __shfl_xor(u2, 1);
            u1 += __shfl_xor(u1, 2); u2 += __shfl_xor(u2, 2);
            u1 += __shfl_xor(u1, 4); u2 += __shfl_xor(u2, 4);
            u1 += __shfl_xor(u1, 8); u2 += __shfl_xor(u2, 8);
            sra[r] = u1; srb[r] = u2;
        }
        if (nl == 0) {
            #pragma unroll
            for (int r = 0; r < 4; ++r) {
                int ea = eB1 + rq * 4 + r;
                if (ea < e1) out[ea] = 1.f / (1.f + __expf(-(sra[r] + c3s)));
                int eb = eB2 + rq * 4 + r;
                if (eb < e1) out[eb] = 1.f / (1.f + __expf(-(srb[r] + c3s)));
            }
        }
    }
}

// ---------------------------------------------------------------------------
extern "C" void kernel_launch(void* const* d_in, const int* in_sizes, int n_in,
                              void* d_out, int out_size, void* d_ws, size_t ws_size,
                              hipStream_t stream) {
    const float* x     = (const float*)d_in[0];
    const float* u     = (const float*)d_in[1];
    const int*   batch = (const int*)  d_in[2];
    const int*   hidx  = (const int*)  d_in[3];
    const int*   bh    = (const int*)  d_in[4];
    const float* W1 = (const float*)d_in[6];
    const float* b1 = (const float*)d_in[7];
    const float* W2 = (const float*)d_in[8];
    const float* b2 = (const float*)d_in[9];
    const float* W3 = (const float*)d_in[10];
    const float* b3 = (const float*)d_in[11];
    const float* Wg = (const float*)d_in[12];
    const float* V1 = (const float*)d_in[13];
    const float* c1 = (const float*)d_in[14];
    const float* V2 = (const float*)d_in[15];
    const float* c2 = (const float*)d_in[16];
    const float* V3 = (const float*)d_in[17];
    const float* c3 = (const float*)d_in[18];

    const int N = in_sizes[0] / 6;
    const int G = in_sizes[1] / 4;
    const int E = in_sizes[4];

    // ws layout
    char* ws = (char*)d_ws;
    size_t off = 0;
    u16* hb = (u16*)(ws + off);            off += (size_t)N * 64 * 2;
    int* seg_start = (int*)(ws + off);     off += ((size_t)G + 1) * 4;
    off = (off + 255) & ~(size_t)255;
    u16* SWZ = (u16*)(ws + off);           off += 20480 * 2;
    float* Sinv = (float*)(ws + off);      off += (size_t)G * 64 * 4;
    off = (off + 255) & ~(size_t)255;
    u16* Xh = (u16*)(ws + off);            off += (size_t)E * 64 * 2;
    float* out = (float*)d_out;

    const int prep_blocks = 32 + (G + 256) / 256;
    prep_kernel<<<prep_blocks, 256, 0, stream>>>(Wg, V1, V2, SWZ, bh, E, G, seg_start);
    node_mlp_kernel<<<(N + 15) / 16, 256, 0, stream>>>(
        x, u, batch, W1, b1, W2, b2, W3, b3, hb, N);
    gather_stats_kernel<<<G, 256, 0, stream>>>(hb, hidx, seg_start, Xh, Sinv, out, E);
    mfma_seg_kernel<<<G, 256, 0, stream>>>(
        Xh, seg_start, SWZ, Sinv, c1, c2, V3, c3, out, E);
}

// Round 13
// 252.058 us; speedup vs baseline: 2.0485x; 1.0726x over previous
//
#include <hip/hip_runtime.h>
#include <math.h>

typedef short bf16x8 __attribute__((ext_vector_type(8)));
typedef float f32x4  __attribute__((ext_vector_type(4)));
typedef unsigned short u16;
typedef unsigned int   u32;

#define MFMA16 __builtin_amdgcn_mfma_f32_16x16x32_bf16

__device__ __forceinline__ u16 f2b(float x) {   // fp32 -> bf16 RNE
    union { float f; unsigned u; } v; v.f = x;
    unsigned r = v.u + 0x7fffu + ((v.u >> 16) & 1u);
    return (u16)(r >> 16);
}
// round-half-up bf16 (2 VALU vs 4; <=0.5ulp; used ONLY for K4's Xhat/O1
// intermediate quantization -- Xh/h/weights stay RNE for exp consistency)
__device__ __forceinline__ u16 f2bu(float x) {
    union { float f; unsigned u; } v; v.f = x;
    return (u16)((v.u + 0x8000u) >> 16);
}
__device__ __forceinline__ float b2f(u16 h) {
    union { unsigned u; float f; } v; v.u = ((unsigned)h) << 16;
    return v.f;
}
__device__ __forceinline__ float blo(u32 w) {
    union { u32 u; float f; } v; v.u = w << 16; return v.f;
}
__device__ __forceinline__ float bhi(u32 w) {
    union { u32 u; float f; } v; v.u = w & 0xffff0000u; return v.f;
}
// sum 3 packed bf16 pairs in fp32 (order i0+i1+i2), repack bf16 RNE
__device__ __forceinline__ u32 add3pack(u32 x, u32 y, u32 z) {
    float lo = blo(x) + blo(y) + blo(z);
    float hi = bhi(x) + bhi(y) + bhi(z);
    return (u32)f2b(lo) | ((u32)f2b(hi) << 16);
}

// ---------------------------------------------------------------------------
// K0+K2 merged: blocks 0..31 pre-swizzle weights into SWZ; remaining blocks
// compute segment bounds (batch_hyper sorted).
// Panel(kt,nt): 16 n-rows x 40 u16. SWZ: WB[0,5120)|V1B[5120,15360)|V2B[15360,20480)
// ---------------------------------------------------------------------------
__global__ __launch_bounds__(256) void prep_kernel(
    const float* __restrict__ Wg, const float* __restrict__ V1g,
    const float* __restrict__ V2g, u16* __restrict__ SWZ,
    const int* __restrict__ bh, int E, int G, int* __restrict__ seg_start)
{
    const int b = blockIdx.x, tid = threadIdx.x;
    if (b < 32) {
        int idx = b * 256 + tid;        // 0..8191
        int k = idx >> 6, n = idx & 63;
        int off = ((k >> 5) * 4 + (n >> 4)) * 640 + (n & 15) * 40 + ((k >> 3) & 3) * 8 + (k & 7);
        SWZ[5120 + off] = f2b(V1g[idx]);
        if (idx < 4096) {
            SWZ[off]         = f2b(Wg[idx]);
            SWZ[15360 + off] = f2b(V2g[idx]);
        }
    } else {
        int g = (b - 32) * 256 + tid;
        if (g > G) return;
        int lo = 0, hi = E;
        while (lo < hi) {
            int mid = (lo + hi) >> 1;
            if (bh[mid] < g) lo = mid + 1; else hi = mid;
        }
        seg_start[g] = lo;
    }
}

// ---------------------------------------------------------------------------
// K1: node MLP -> hb (bf16) [N,64]. 16 nodes/block, 4 nodes/thread
// (R12-verified): W2/W3 scalar loads amortized 4x. h bit-identical to R10.
// ---------------------------------------------------------------------------
__global__ __launch_bounds__(256) void node_mlp_kernel(
    const float* __restrict__ x, const float* __restrict__ u,
    const int* __restrict__ batch,
    const float* __restrict__ W1, const float* __restrict__ b1,
    const float* __restrict__ W2, const float* __restrict__ b2,
    const float* __restrict__ W3, const float* __restrict__ b3,
    u16* __restrict__ hb, int N)
{
    __shared__ float inbuf[16][10];
    __shared__ float h1[16][64];
    __shared__ float h2[16][64];
    const int tid = threadIdx.x;
    const int ni = tid >> 6, f = tid & 63;
    const int base = blockIdx.x * 16;
    int nodes[4];
    #pragma unroll
    for (int s = 0; s < 4; ++s) {
        nodes[s] = min(base + s * 4 + ni, N - 1);
        if (f < 6)       inbuf[s * 4 + ni][f] = x[nodes[s] * 6 + f];
        else if (f < 10) inbuf[s * 4 + ni][f] = u[batch[nodes[s]] * 4 + (f - 6)];
    }
    __syncthreads();
    float acc[4];
    #pragma unroll
    for (int s = 0; s < 4; ++s) acc[s] = b1[f];
    #pragma unroll
    for (int k = 0; k < 10; ++k) {
        float w = W1[k * 64 + f];
        #pragma unroll
        for (int s = 0; s < 4; ++s) acc[s] = fmaf(inbuf[s * 4 + ni][k], w, acc[s]);
    }
    #pragma unroll
    for (int s = 0; s < 4; ++s) h1[s * 4 + ni][f] = fmaxf(acc[s], 0.f);
    __syncthreads();
    #pragma unroll
    for (int s = 0; s < 4; ++s) acc[s] = b2[f];
    #pragma unroll
    for (int k4 = 0; k4 < 16; ++k4) {
        float w0 = W2[(k4 * 4 + 0) * 64 + f];
        float w1 = W2[(k4 * 4 + 1) * 64 + f];
        float w2 = W2[(k4 * 4 + 2) * 64 + f];
        float w3 = W2[(k4 * 4 + 3) * 64 + f];
        #pragma unroll
        for (int s = 0; s < 4; ++s) {
            float4 hv = *(const float4*)&h1[s * 4 + ni][k4 * 4];
            acc[s] = fmaf(hv.x, w0, acc[s]);
            acc[s] = fmaf(hv.y, w1, acc[s]);
            acc[s] = fmaf(hv.z, w2, acc[s]);
            acc[s] = fmaf(hv.w, w3, acc[s]);
        }
    }
    #pragma unroll
    for (int s = 0; s < 4; ++s) h2[s * 4 + ni][f] = fmaxf(acc[s], 0.f);
    __syncthreads();
    #pragma unroll
    for (int s = 0; s < 4; ++s) acc[s] = b3[f];
    #pragma unroll
    for (int k4 = 0; k4 < 16; ++k4) {
        float w0 = W3[(k4 * 4 + 0) * 64 + f];
        float w1 = W3[(k4 * 4 + 1) * 64 + f];
        float w2 = W3[(k4 * 4 + 2) * 64 + f];
        float w3 = W3[(k4 * 4 + 3) * 64 + f];
        #pragma unroll
        for (int s = 0; s < 4; ++s) {
            float4 hv = *(const float4*)&h2[s * 4 + ni][k4 * 4];
            acc[s] = fmaf(hv.x, w0, acc[s]);
            acc[s] = fmaf(hv.y, w1, acc[s]);
            acc[s] = fmaf(hv.z, w2, acc[s]);
            acc[s] = fmaf(hv.w, w3, acc[s]);
        }
    }
    #pragma unroll
    for (int s = 0; s < 4; ++s) hb[nodes[s] * 64 + f] = f2b(acc[s]);
}

// ---------------------------------------------------------------------------
// K3: gather + Xh write + softmax denominators + out[E..2E) writes.
// uint4 gathers (R12-verified). Standalone at high occupancy (R8 lesson).
// exp of the RNE-rounded sum (matches K4's A-frags exactly).
// ---------------------------------------------------------------------------
__global__ __launch_bounds__(256) void gather_stats_kernel(
    const u16* __restrict__ hb, const int* __restrict__ hidx,
    const int* __restrict__ seg_start,
    u16* __restrict__ Xh, float* __restrict__ Sinv,
    float* __restrict__ out, int E)
{
    __shared__ float ps[4][8][8];
    const int tid = threadIdx.x, lane = tid & 63, wid = tid >> 6;
    const int sub = lane >> 3, cl = lane & 7;    // sub: edge, cl: col-group of 8
    const int g = blockIdx.x;
    const int e0 = seg_start[g], e1 = seg_start[g + 1];
    if (e1 <= e0) return;                        // uniform across block
    const int e1m1 = e1 - 1;
    const float gf = (float)g;

    for (int e = e0 + tid; e < e1; e += 256) out[E + e] = gf;   // coalesced

    float s[8] = {0.f, 0.f, 0.f, 0.f, 0.f, 0.f, 0.f, 0.f};
    for (int e = e0 + wid * 8 + sub; e < e1; e += 128) {
        #pragma unroll
        for (int j = 0; j < 4; ++j) {
            int ee = e + j * 32;
            int ec = min(ee, e1m1);
            int i0 = hidx[ec], i1 = hidx[E + ec], i2 = hidx[2 * E + ec];
            uint4 A0 = *(const uint4*)(hb + (size_t)i0 * 64 + cl * 8);
            uint4 A1 = *(const uint4*)(hb + (size_t)i1 * 64 + cl * 8);
            uint4 A2 = *(const uint4*)(hb + (size_t)i2 * 64 + cl * 8);
            u32 w0 = add3pack(A0.x, A1.x, A2.x);
            u32 w1 = add3pack(A0.y, A1.y, A2.y);
            u32 w2 = add3pack(A0.z, A1.z, A2.z);
            u32 w3 = add3pack(A0.w, A1.w, A2.w);
            if (ee < e1) {
                uint4 W; W.x = w0; W.y = w1; W.z = w2; W.w = w3;
                *(uint4*)(Xh + (size_t)ee * 64 + cl * 8) = W;
                s[0] += __expf(blo(w0)); s[1] += __expf(bhi(w0));
                s[2] += __expf(blo(w1)); s[3] += __expf(bhi(w1));
                s[4] += __expf(blo(w2)); s[5] += __expf(bhi(w2));
                s[6] += __expf(blo(w3)); s[7] += __expf(bhi(w3));
            }
        }
    }
    #pragma unroll
    for (int k = 0; k < 8; ++k) {
        s[k] += __shfl_xor(s[k], 8);
        s[k] += __shfl_xor(s[k], 16);
        s[k] += __shfl_xor(s[k], 32);
    }
    if (lane < 8) {
        #pragma unroll
        for (int k = 0; k < 8; ++k) ps[wid][lane][k] = s[k];
    }
    __syncthreads();
    if (tid < 64) {
        int c8 = tid >> 3, cc = tid & 7;
        float S = ps[0][c8][cc] + ps[1][c8][cc] + ps[2][c8][cc] + ps[3][c8][cc];
        Sinv[g * 64 + tid] = 1.f / S;
    }
}

// ---------------------------------------------------------------------------
// K4: paired-tile MFMA chain (R11-verified structure) + f2bu epilogues.
// XT stride REVERTED to 72 u16: stride must keep 16B alignment (72*2=144,
// 144%16==0 -> ds_read_b128 legal; R12's 76 -> 152B broke alignment for odd
// nl, splitting reads into b64 pairs = the 89->107us regression). Stride-72
// b128 reads are throughput-uniform (8 lanes/bank-group = the wave64-b128
// minimum) — NOT a real conflict. [R12/R13 lesson]
// Locked: 256-thr blocks + (256,3) (R9), weights in LDS (R5), Xh streamed
// w/ prefetch (R7). LDS: 40960(SW) + 9216(XT) = 50176 B -> 3 blocks/CU.
// ---------------------------------------------------------------------------
__global__ __launch_bounds__(256, 3) void mfma_seg_kernel(
    const u16* __restrict__ Xh, const int* __restrict__ seg_start,
    const u16* __restrict__ SWZ, const float* __restrict__ Sinv,
    const float* __restrict__ c1g, const float* __restrict__ c2g,
    const float* __restrict__ V3g, const float* __restrict__ c3g,
    float* __restrict__ out, int E)
{
    __shared__ u16 SW[20480];          // WB[0,5120)+V1B[5120,15360)+V2B[15360,20480)
    __shared__ u16 XT_all[4][16 * 72]; // per-wave transpose tile, stride 72

    const int tid = threadIdx.x, lane = tid & 63, wid = tid >> 6;
    const int nl = lane & 15, rq = lane >> 4;
    const int g = blockIdx.x;
    const int e0 = seg_start[g], e1 = seg_start[g + 1];
    const int L = e1 - e0;
    if (L <= 0) return;
    const int e1m1 = e1 - 1;

    {   // stage pre-swizzled W+V1+V2: 40960 B = 2560 uint4
        const uint4* src = (const uint4*)SWZ;
        uint4* dst = (uint4*)SW;
        for (int i = tid; i < 2560; i += 256) dst[i] = src[i];
    }
    __syncthreads();
    const u16* WB  = SW;
    const u16* V1B = SW + 5120;
    const u16* V2B = SW + 15360;

    // identity B-frags for X C-layout redistribution (exact in bf16)
    bf16x8 I0, I1;
    #pragma unroll
    for (int j = 0; j < 8; ++j) {
        I0[j] = (rq * 8 + j == nl)      ? (short)0x3F80 : (short)0;
        I1[j] = (rq * 8 + j == nl + 16) ? (short)0x3F80 : (short)0;
    }

    float dinvv[4], c1v[4], c2v[4], v3v[4];
    #pragma unroll
    for (int nt = 0; nt < 4; ++nt) {
        int col = nt * 16 + nl;
        dinvv[nt] = Sinv[g * 64 + col];
        c1v[nt]   = c1g[col];
        c2v[nt]   = c2g[col];
        v3v[nt]   = V3g[col];
    }
    const float c3s = c3g[0];
    u16* XT = XT_all[wid];
    const f32x4 zf = {0.f, 0.f, 0.f, 0.f};

    auto loadA = [&](int tt, bf16x8& A0, bf16x8& A1) {
        const u16* xp = Xh + (size_t)min(e0 + tt * 16 + nl, e1m1) * 64 + rq * 8;
        A0 = *(const bf16x8*)(xp);
        A1 = *(const bf16x8*)(xp + 32);
    };

    int t = wid;
    bf16x8 p0 = {}, p1 = {};
    if (t * 16 < L) loadA(t, p0, p1);

    for (; t * 16 < L; t += 8) {
        const int eB1 = e0 + t * 16;
        const int eB2 = eB1 + 64;                 // tile t+4 (may be phantom)

        bf16x8 a0 = p0, a1 = p1;                  // tile 1 (prefetched)
        bf16x8 a2, a3;
        loadA(t + 4, a2, a3);                     // tile 2 (clamped)
        if ((t + 8) * 16 < L) loadA(t + 8, p0, p1);  // prefetch next pair's 1st

        // xv in C-layout via identity MFMA, both tiles
        f32x4 xc1[4], xc2[4];
        xc1[0] = MFMA16(a0, I0, zf, 0, 0, 0);
        xc1[1] = MFMA16(a0, I1, zf, 0, 0, 0);
        xc1[2] = MFMA16(a1, I0, zf, 0, 0, 0);
        xc1[3] = MFMA16(a1, I1, zf, 0, 0, 0);
        xc2[0] = MFMA16(a2, I0, zf, 0, 0, 0);
        xc2[1] = MFMA16(a2, I1, zf, 0, 0, 0);
        xc2[2] = MFMA16(a3, I0, zf, 0, 0, 0);
        xc2[3] = MFMA16(a3, I1, zf, 0, 0, 0);

        // ---- layer W (B-frags shared) ----
        f32x4 acc1[4] = {zf, zf, zf, zf}, acc2t[4] = {zf, zf, zf, zf};
        #pragma unroll
        for (int nt = 0; nt < 4; ++nt) {
            bf16x8 b0 = *(const bf16x8*)(WB + (0 * 4 + nt) * 640 + nl * 40 + rq * 8);
            acc1[nt]  = MFMA16(a0, b0, acc1[nt], 0, 0, 0);
            acc2t[nt] = MFMA16(a2, b0, acc2t[nt], 0, 0, 0);
            bf16x8 b1 = *(const bf16x8*)(WB + (1 * 4 + nt) * 640 + nl * 40 + rq * 8);
            acc1[nt]  = MFMA16(a1, b1, acc1[nt], 0, 0, 0);
            acc2t[nt] = MFMA16(a3, b1, acc2t[nt], 0, 0, 0);
        }
        // Xhat epilogue tile1 -> XT, read x-frags; then tile2 (region reuse)
        #pragma unroll
        for (int nt = 0; nt < 4; ++nt) {
            #pragma unroll
            for (int r = 0; r < 4; ++r) {
                float coef = __expf(xc1[nt][r]) * dinvv[nt];
                XT[(rq * 4 + r) * 72 + nt * 16 + nl] =
                    f2bu(coef * fmaxf(acc1[nt][r], 0.f));
            }
        }
        bf16x8 x2a = *(const bf16x8*)(XT + nl * 72 + rq * 8);
        bf16x8 x3a = *(const bf16x8*)(XT + nl * 72 + 32 + rq * 8);
        #pragma unroll
        for (int nt = 0; nt < 4; ++nt) {
            #pragma unroll
            for (int r = 0; r < 4; ++r) {
                float coef = __expf(xc2[nt][r]) * dinvv[nt];
                XT[(rq * 4 + r) * 72 + nt * 16 + nl] =
                    f2bu(coef * fmaxf(acc2t[nt][r], 0.f));
            }
        }
        bf16x8 x2b = *(const bf16x8*)(XT + nl * 72 + rq * 8);
        bf16x8 x3b = *(const bf16x8*)(XT + nl * 72 + 32 + rq * 8);

        // ---- layer V1 (B-frags shared) ----
        f32x4 va[4], vb[4];
        #pragma unroll
        for (int nt = 0; nt < 4; ++nt) {
            va[nt][0] = c1v[nt]; va[nt][1] = c1v[nt];
            va[nt][2] = c1v[nt]; va[nt][3] = c1v[nt];
            vb[nt] = va[nt];
        }
        #pragma unroll
        for (int nt = 0; nt < 4; ++nt) {
            bf16x8 b0 = *(const bf16x8*)(V1B + (0 * 4 + nt) * 640 + nl * 40 + rq * 8);
            va[nt] = MFMA16(a0, b0, va[nt], 0, 0, 0);
            vb[nt] = MFMA16(a2, b0, vb[nt], 0, 0, 0);
            bf16x8 b1 = *(const bf16x8*)(V1B + (1 * 4 + nt) * 640 + nl * 40 + rq * 8);
            va[nt] = MFMA16(a1, b1, va[nt], 0, 0, 0);
            vb[nt] = MFMA16(a3, b1, vb[nt], 0, 0, 0);
        }
        #pragma unroll
        for (int nt = 0; nt < 4; ++nt) {
            bf16x8 b2 = *(const bf16x8*)(V1B + (2 * 4 + nt) * 640 + nl * 40 + rq * 8);
            va[nt] = MFMA16(x2a, b2, va[nt], 0, 0, 0);
            vb[nt] = MFMA16(x2b, b2, vb[nt], 0, 0, 0);
            bf16x8 b3 = *(const bf16x8*)(V1B + (3 * 4 + nt) * 640 + nl * 40 + rq * 8);
            va[nt] = MFMA16(x3a, b3, va[nt], 0, 0, 0);
            vb[nt] = MFMA16(x3b, b3, vb[nt], 0, 0, 0);
        }
        // O1 epilogue tile1 -> XT, read o-frags; then tile2
        #pragma unroll
        for (int nt = 0; nt < 4; ++nt) {
            #pragma unroll
            for (int r = 0; r < 4; ++r)
                XT[(rq * 4 + r) * 72 + nt * 16 + nl] = f2bu(fmaxf(va[nt][r], 0.f));
        }
        bf16x8 o0a = *(const bf16x8*)(XT + nl * 72 + rq * 8);
        bf16x8 o1a = *(const bf16x8*)(XT + nl * 72 + 32 + rq * 8);
        #pragma unroll
        for (int nt = 0; nt < 4; ++nt) {
            #pragma unroll
            for (int r = 0; r < 4; ++r)
                XT[(rq * 4 + r) * 72 + nt * 16 + nl] = f2bu(fmaxf(vb[nt][r], 0.f));
        }
        bf16x8 o0b = *(const bf16x8*)(XT + nl * 72 + rq * 8);
        bf16x8 o1b = *(const bf16x8*)(XT + nl * 72 + 32 + rq * 8);

        // ---- layer V2 (B-frags shared) ----
        f32x4 wa[4], wb2[4];
        #pragma unroll
        for (int nt = 0; nt < 4; ++nt) {
            wa[nt][0] = c2v[nt]; wa[nt][1] = c2v[nt];
            wa[nt][2] = c2v[nt]; wa[nt][3] = c2v[nt];
            wb2[nt] = wa[nt];
        }
        #pragma unroll
        for (int nt = 0; nt < 4; ++nt) {
            bf16x8 b0 = *(const bf16x8*)(V2B + (0 * 4 + nt) * 640 + nl * 40 + rq * 8);
            wa[nt]  = MFMA16(o0a, b0, wa[nt], 0, 0, 0);
            wb2[nt] = MFMA16(o0b, b0, wb2[nt], 0, 0, 0);
            bf16x8 b1 = *(const bf16x8*)(V2B + (1 * 4 + nt) * 640 + nl * 40 + rq * 8);
            wa[nt]  = MFMA16(o1a, b1, wa[nt], 0, 0, 0);
            wb2[nt] = MFMA16(o1b, b1, wb2[nt], 0, 0, 0);
        }

        // ---- V3 + sigmoid, both tiles ----
        float sra[4], srb[4];
        #pragma unroll
        for (int r = 0; r < 4; ++r) {
            float u1 = 0.f, u2 = 0.f;
            #pragma unroll
            for (int nt = 0; nt < 4; ++nt) {
                u1 = fmaf(fmaxf(wa[nt][r],  0.f), v3v[nt], u1);
                u2 = fmaf(fmaxf(wb2[nt][r], 0.f), v3v[nt], u2);
            }
            u1 += __shfl_xor(u1, 1); u2 += __shfl_xor(u2, 1);
            u1 += __shfl_xor(u1, 2); u2 += __shfl_xor(u2, 2);
            u1 += __shfl_xor(u1, 4); u2 += __shfl_xor(u2, 4);
            u1 += __shfl_xor(u1, 8); u2 += __shfl_xor(u2, 8);
            sra[r] = u1; srb[r] = u2;
        }
        if (nl == 0) {
            #pragma unroll
            for (int r = 0; r < 4; ++r) {
                int ea = eB1 + rq * 4 + r;
                if (ea < e1) out[ea] = 1.f / (1.f + __expf(-(sra[r] + c3s)));
                int eb = eB2 + rq * 4 + r;
                if (eb < e1) out[eb] = 1.f / (1.f + __expf(-(srb[r] + c3s)));
            }
        }
    }
}

// ---------------------------------------------------------------------------
extern "C" void kernel_launch(void* const* d_in, const int* in_sizes, int n_in,
                              void* d_out, int out_size, void* d_ws, size_t ws_size,
                              hipStream_t stream) {
    const float* x     = (const float*)d_in[0];
    const float* u     = (const float*)d_in[1];
    const int*   batch = (const int*)  d_in[2];
    const int*   hidx  = (const int*)  d_in[3];
    const int*   bh    = (const int*)  d_in[4];
    const float* W1 = (const float*)d_in[6];
    const float* b1 = (const float*)d_in[7];
    const float* W2 = (const float*)d_in[8];
    const float* b2 = (const float*)d_in[9];
    const float* W3 = (const float*)d_in[10];
    const float* b3 = (const float*)d_in[11];
    const float* Wg = (const float*)d_in[12];
    const float* V1 = (const float*)d_in[13];
    const float* c1 = (const float*)d_in[14];
    const float* V2 = (const float*)d_in[15];
    const float* c2 = (const float*)d_in[16];
    const float* V3 = (const float*)d_in[17];
    const float* c3 = (const float*)d_in[18];

    const int N = in_sizes[0] / 6;
    const int G = in_sizes[1] / 4;
    const int E = in_sizes[4];

    // ws layout
    char* ws = (char*)d_ws;
    size_t off = 0;
    u16* hb = (u16*)(ws + off);            off += (size_t)N * 64 * 2;
    int* seg_start = (int*)(ws + off);     off += ((size_t)G + 1) * 4;
    off = (off + 255) & ~(size_t)255;
    u16* SWZ = (u16*)(ws + off);           off += 20480 * 2;
    float* Sinv = (float*)(ws + off);      off += (size_t)G * 64 * 4;
    off = (off + 255) & ~(size_t)255;
    u16* Xh = (u16*)(ws + off);            off += (size_t)E * 64 * 2;
    float* out = (float*)d_out;

    const int prep_blocks = 32 + (G + 256) / 256;
    prep_kernel<<<prep_blocks, 256, 0, stream>>>(Wg, V1, V2, SWZ, bh, E, G, seg_start);
    node_mlp_kernel<<<(N + 15) / 16, 256, 0, stream>>>(
        x, u, batch, W1, b1, W2, b2, W3, b3, hb, N);
    gather_stats_kernel<<<G, 256, 0, stream>>>(hb, hidx, seg_start, Xh, Sinv, out, E);
    mfma_seg_kernel<<<G, 256, 0, stream>>>(
        Xh, seg_start, SWZ, Sinv, c1, c2, V3, c3, out, E);
}

// Round 14
// 245.639 us; speedup vs baseline: 2.1021x; 1.0261x over previous
//
#include <hip/hip_runtime.h>
#include <math.h>

typedef short bf16x8 __attribute__((ext_vector_type(8)));
typedef float f32x4  __attribute__((ext_vector_type(4)));
typedef unsigned short u16;
typedef unsigned int   u32;

#define MFMA16 __builtin_amdgcn_mfma_f32_16x16x32_bf16

__device__ __forceinline__ u16 f2b(float x) {   // fp32 -> bf16 RNE
    union { float f; unsigned u; } v; v.f = x;
    unsigned r = v.u + 0x7fffu + ((v.u >> 16) & 1u);
    return (u16)(r >> 16);
}
// round-half-up bf16 (2 VALU vs 4; <=0.5ulp) — K4 Xhat/O1 quantization
__device__ __forceinline__ u16 f2bu(float x) {
    union { float f; unsigned u; } v; v.f = x;
    return (u16)((v.u + 0x8000u) >> 16);
}
__device__ __forceinline__ float b2f(u16 h) {
    union { unsigned u; float f; } v; v.u = ((unsigned)h) << 16;
    return v.f;
}
__device__ __forceinline__ float blo(u32 w) {
    union { u32 u; float f; } v; v.u = w << 16; return v.f;
}
__device__ __forceinline__ float bhi(u32 w) {
    union { u32 u; float f; } v; v.u = w & 0xffff0000u; return v.f;
}
// sum 3 packed bf16 pairs in fp32 (order i0+i1+i2), repack bf16 HALF-UP via
// one v_perm_b32: 3 instr/pair vs 10 (R14: K3 VALU cut). Consistency: exp
// and K4 A-frags both read the STORED rounded value.
__device__ __forceinline__ u32 add3pack(u32 x, u32 y, u32 z) {
    union { float f; u32 u; } lo, hi;
    lo.f = blo(x) + blo(y) + blo(z);
    hi.f = bhi(x) + bhi(y) + bhi(z);
    return __builtin_amdgcn_perm(hi.u + 0x8000u, lo.u + 0x8000u, 0x07060302u);
}

// ---------------------------------------------------------------------------
// K1 (merged): blocks [0,32) pre-swizzle weights into SWZ; blocks [32,32+SB)
// segment bounds; blocks [32+SB, ...) node MLP -> hb (bf16) [N,64].
// Node-MLP part R12-verified (16 nodes/block, 4 nodes/thread, h
// bit-identical). Merge saves one launch boundary.
// Panel(kt,nt): 16 n-rows x 40 u16. SWZ: WB[0,5120)|V1B[5120,15360)|V2B[15360,20480)
// ---------------------------------------------------------------------------
__global__ __launch_bounds__(256) void prep_mlp_kernel(
    const float* __restrict__ x, const float* __restrict__ u,
    const int* __restrict__ batch,
    const float* __restrict__ W1, const float* __restrict__ b1,
    const float* __restrict__ W2, const float* __restrict__ b2,
    const float* __restrict__ W3, const float* __restrict__ b3,
    u16* __restrict__ hb, int N,
    const float* __restrict__ Wg, const float* __restrict__ V1g,
    const float* __restrict__ V2g, u16* __restrict__ SWZ,
    const int* __restrict__ bh, int E, int G, int* __restrict__ seg_start,
    int SB)
{
    const int b = blockIdx.x, tid = threadIdx.x;
    if (b < 32) {                       // ---- weight swizzle ----
        int idx = b * 256 + tid;        // 0..8191
        int k = idx >> 6, n = idx & 63;
        int off = ((k >> 5) * 4 + (n >> 4)) * 640 + (n & 15) * 40 + ((k >> 3) & 3) * 8 + (k & 7);
        SWZ[5120 + off] = f2b(V1g[idx]);
        if (idx < 4096) {
            SWZ[off]         = f2b(Wg[idx]);
            SWZ[15360 + off] = f2b(V2g[idx]);
        }
        return;
    }
    if (b < 32 + SB) {                  // ---- segment bounds ----
        int g = (b - 32) * 256 + tid;
        if (g > G) return;
        int lo = 0, hi = E;
        while (lo < hi) {
            int mid = (lo + hi) >> 1;
            if (bh[mid] < g) lo = mid + 1; else hi = mid;
        }
        seg_start[g] = lo;
        return;
    }
    // ---- node MLP ----
    __shared__ float inbuf[16][10];
    __shared__ float h1[16][64];
    __shared__ float h2[16][64];
    const int ni = tid >> 6, f = tid & 63;
    const int base = (b - 32 - SB) * 16;
    int nodes[4];
    #pragma unroll
    for (int s = 0; s < 4; ++s) {
        nodes[s] = min(base + s * 4 + ni, N - 1);
        if (f < 6)       inbuf[s * 4 + ni][f] = x[nodes[s] * 6 + f];
        else if (f < 10) inbuf[s * 4 + ni][f] = u[batch[nodes[s]] * 4 + (f - 6)];
    }
    __syncthreads();
    float acc[4];
    #pragma unroll
    for (int s = 0; s < 4; ++s) acc[s] = b1[f];
    #pragma unroll
    for (int k = 0; k < 10; ++k) {
        float w = W1[k * 64 + f];
        #pragma unroll
        for (int s = 0; s < 4; ++s) acc[s] = fmaf(inbuf[s * 4 + ni][k], w, acc[s]);
    }
    #pragma unroll
    for (int s = 0; s < 4; ++s) h1[s * 4 + ni][f] = fmaxf(acc[s], 0.f);
    __syncthreads();
    #pragma unroll
    for (int s = 0; s < 4; ++s) acc[s] = b2[f];
    #pragma unroll
    for (int k4 = 0; k4 < 16; ++k4) {
        float w0 = W2[(k4 * 4 + 0) * 64 + f];
        float w1 = W2[(k4 * 4 + 1) * 64 + f];
        float w2 = W2[(k4 * 4 + 2) * 64 + f];
        float w3 = W2[(k4 * 4 + 3) * 64 + f];
        #pragma unroll
        for (int s = 0; s < 4; ++s) {
            float4 hv = *(const float4*)&h1[s * 4 + ni][k4 * 4];
            acc[s] = fmaf(hv.x, w0, acc[s]);
            acc[s] = fmaf(hv.y, w1, acc[s]);
            acc[s] = fmaf(hv.z, w2, acc[s]);
            acc[s] = fmaf(hv.w, w3, acc[s]);
        }
    }
    #pragma unroll
    for (int s = 0; s < 4; ++s) h2[s * 4 + ni][f] = fmaxf(acc[s], 0.f);
    __syncthreads();
    #pragma unroll
    for (int s = 0; s < 4; ++s) acc[s] = b3[f];
    #pragma unroll
    for (int k4 = 0; k4 < 16; ++k4) {
        float w0 = W3[(k4 * 4 + 0) * 64 + f];
        float w1 = W3[(k4 * 4 + 1) * 64 + f];
        float w2 = W3[(k4 * 4 + 2) * 64 + f];
        float w3 = W3[(k4 * 4 + 3) * 64 + f];
        #pragma unroll
        for (int s = 0; s < 4; ++s) {
            float4 hv = *(const float4*)&h2[s * 4 + ni][k4 * 4];
            acc[s] = fmaf(hv.x, w0, acc[s]);
            acc[s] = fmaf(hv.y, w1, acc[s]);
            acc[s] = fmaf(hv.z, w2, acc[s]);
            acc[s] = fmaf(hv.w, w3, acc[s]);
        }
    }
    #pragma unroll
    for (int s = 0; s < 4; ++s) hb[nodes[s] * 64 + f] = f2b(acc[s]);
}

// ---------------------------------------------------------------------------
// K3: gather + Xh write + softmax denominators + out[E..2E) writes.
// uint4 gathers (R12-verified); add3pack now perm-based half-up (R14,
// ~35% VALU cut). Standalone at high occupancy (R8 lesson). exp reads the
// STORED rounded value (matches K4's A-frags exactly).
// ---------------------------------------------------------------------------
__global__ __launch_bounds__(256) void gather_stats_kernel(
    const u16* __restrict__ hb, const int* __restrict__ hidx,
    const int* __restrict__ seg_start,
    u16* __restrict__ Xh, float* __restrict__ Sinv,
    float* __restrict__ out, int E)
{
    __shared__ float ps[4][8][8];
    const int tid = threadIdx.x, lane = tid & 63, wid = tid >> 6;
    const int sub = lane >> 3, cl = lane & 7;    // sub: edge, cl: col-group of 8
    const int g = blockIdx.x;
    const int e0 = seg_start[g], e1 = seg_start[g + 1];
    if (e1 <= e0) return;                        // uniform across block
    const int e1m1 = e1 - 1;
    const float gf = (float)g;

    for (int e = e0 + tid; e < e1; e += 256) out[E + e] = gf;   // coalesced

    float s[8] = {0.f, 0.f, 0.f, 0.f, 0.f, 0.f, 0.f, 0.f};
    for (int e = e0 + wid * 8 + sub; e < e1; e += 128) {
        #pragma unroll
        for (int j = 0; j < 4; ++j) {
            int ee = e + j * 32;
            int ec = min(ee, e1m1);
            int i0 = hidx[ec], i1 = hidx[E + ec], i2 = hidx[2 * E + ec];
            uint4 A0 = *(const uint4*)(hb + (size_t)i0 * 64 + cl * 8);
            uint4 A1 = *(const uint4*)(hb + (size_t)i1 * 64 + cl * 8);
            uint4 A2 = *(const uint4*)(hb + (size_t)i2 * 64 + cl * 8);
            u32 w0 = add3pack(A0.x, A1.x, A2.x);
            u32 w1 = add3pack(A0.y, A1.y, A2.y);
            u32 w2 = add3pack(A0.z, A1.z, A2.z);
            u32 w3 = add3pack(A0.w, A1.w, A2.w);
            if (ee < e1) {
                uint4 W; W.x = w0; W.y = w1; W.z = w2; W.w = w3;
                *(uint4*)(Xh + (size_t)ee * 64 + cl * 8) = W;
                s[0] += __expf(blo(w0)); s[1] += __expf(bhi(w0));
                s[2] += __expf(blo(w1)); s[3] += __expf(bhi(w1));
                s[4] += __expf(blo(w2)); s[5] += __expf(bhi(w2));
                s[6] += __expf(blo(w3)); s[7] += __expf(bhi(w3));
            }
        }
    }
    #pragma unroll
    for (int k = 0; k < 8; ++k) {
        s[k] += __shfl_xor(s[k], 8);
        s[k] += __shfl_xor(s[k], 16);
        s[k] += __shfl_xor(s[k], 32);
    }
    if (lane < 8) {
        #pragma unroll
        for (int k = 0; k < 8; ++k) ps[wid][lane][k] = s[k];
    }
    __syncthreads();
    if (tid < 64) {
        int c8 = tid >> 3, cc = tid & 7;
        float S = ps[0][c8][cc] + ps[1][c8][cc] + ps[2][c8][cc] + ps[3][c8][cc];
        Sinv[g * 64 + tid] = 1.f / S;
    }
}

// ---------------------------------------------------------------------------
// K4: paired-tile MFMA chain — UNCHANGED from R13 (verified 85us / VGPR 80 /
// no spill). Stride 72 (16B-aligned, R12/R13 lesson), f2bu epilogues,
// 256-thr blocks + (256,3) (R9), weights in LDS (R5), Xh streamed w/
// prefetch (R7). LDS: 40960(SW) + 9216(XT) = 50176 B -> 3 blocks/CU.
// ---------------------------------------------------------------------------
__global__ __launch_bounds__(256, 3) void mfma_seg_kernel(
    const u16* __restrict__ Xh, const int* __restrict__ seg_start,
    const u16* __restrict__ SWZ, const float* __restrict__ Sinv,
    const float* __restrict__ c1g, const float* __restrict__ c2g,
    const float* __restrict__ V3g, const float* __restrict__ c3g,
    float* __restrict__ out, int E)
{
    __shared__ u16 SW[20480];          // WB[0,5120)+V1B[5120,15360)+V2B[15360,20480)
    __shared__ u16 XT_all[4][16 * 72]; // per-wave transpose tile, stride 72

    const int tid = threadIdx.x, lane = tid & 63, wid = tid >> 6;
    const int nl = lane & 15, rq = lane >> 4;
    const int g = blockIdx.x;
    const int e0 = seg_start[g], e1 = seg_start[g + 1];
    const int L = e1 - e0;
    if (L <= 0) return;
    const int e1m1 = e1 - 1;

    {   // stage pre-swizzled W+V1+V2: 40960 B = 2560 uint4
        const uint4* src = (const uint4*)SWZ;
        uint4* dst = (uint4*)SW;
        for (int i = tid; i < 2560; i += 256) dst[i] = src[i];
    }
    __syncthreads();
    const u16* WB  = SW;
    const u16* V1B = SW + 5120;
    const u16* V2B = SW + 15360;

    // identity B-frags for X C-layout redistribution (exact in bf16)
    bf16x8 I0, I1;
    #pragma unroll
    for (int j = 0; j < 8; ++j) {
        I0[j] = (rq * 8 + j == nl)      ? (short)0x3F80 : (short)0;
        I1[j] = (rq * 8 + j == nl + 16) ? (short)0x3F80 : (short)0;
    }

    float dinvv[4], c1v[4], c2v[4], v3v[4];
    #pragma unroll
    for (int nt = 0; nt < 4; ++nt) {
        int col = nt * 16 + nl;
        dinvv[nt] = Sinv[g * 64 + col];
        c1v[nt]   = c1g[col];
        c2v[nt]   = c2g[col];
        v3v[nt]   = V3g[col];
    }
    const float c3s = c3g[0];
    u16* XT = XT_all[wid];
    const f32x4 zf = {0.f, 0.f, 0.f, 0.f};

    auto loadA = [&](int tt, bf16x8& A0, bf16x8& A1) {
        const u16* xp = Xh + (size_t)min(e0 + tt * 16 + nl, e1m1) * 64 + rq * 8;
        A0 = *(const bf16x8*)(xp);
        A1 = *(const bf16x8*)(xp + 32);
    };

    int t = wid;
    bf16x8 p0 = {}, p1 = {};
    if (t * 16 < L) loadA(t, p0, p1);

    for (; t * 16 < L; t += 8) {
        const int eB1 = e0 + t * 16;
        const int eB2 = eB1 + 64;                 // tile t+4 (may be phantom)

        bf16x8 a0 = p0, a1 = p1;                  // tile 1 (prefetched)
        bf16x8 a2, a3;
        loadA(t + 4, a2, a3);                     // tile 2 (clamped)
        if ((t + 8) * 16 < L) loadA(t + 8, p0, p1);  // prefetch next pair's 1st

        // xv in C-layout via identity MFMA, both tiles
        f32x4 xc1[4], xc2[4];
        xc1[0] = MFMA16(a0, I0, zf, 0, 0, 0);
        xc1[1] = MFMA16(a0, I1, zf, 0, 0, 0);
        xc1[2] = MFMA16(a1, I0, zf, 0, 0, 0);
        xc1[3] = MFMA16(a1, I1, zf, 0, 0, 0);
        xc2[0] = MFMA16(a2, I0, zf, 0, 0, 0);
        xc2[1] = MFMA16(a2, I1, zf, 0, 0, 0);
        xc2[2] = MFMA16(a3, I0, zf, 0, 0, 0);
        xc2[3] = MFMA16(a3, I1, zf, 0, 0, 0);

        // ---- layer W (B-frags shared) ----
        f32x4 acc1[4] = {zf, zf, zf, zf}, acc2t[4] = {zf, zf, zf, zf};
        #pragma unroll
        for (int nt = 0; nt < 4; ++nt) {
            bf16x8 b0 = *(const bf16x8*)(WB + (0 * 4 + nt) * 640 + nl * 40 + rq * 8);
            acc1[nt]  = MFMA16(a0, b0, acc1[nt], 0, 0, 0);
            acc2t[nt] = MFMA16(a2, b0, acc2t[nt], 0, 0, 0);
            bf16x8 b1 = *(const bf16x8*)(WB + (1 * 4 + nt) * 640 + nl * 40 + rq * 8);
            acc1[nt]  = MFMA16(a1, b1, acc1[nt], 0, 0, 0);
            acc2t[nt] = MFMA16(a3, b1, acc2t[nt], 0, 0, 0);
        }
        // Xhat epilogue tile1 -> XT, read x-frags; then tile2 (region reuse)
        #pragma unroll
        for (int nt = 0; nt < 4; ++nt) {
            #pragma unroll
            for (int r = 0; r < 4; ++r) {
                float coef = __expf(xc1[nt][r]) * dinvv[nt];
                XT[(rq * 4 + r) * 72 + nt * 16 + nl] =
                    f2bu(coef * fmaxf(acc1[nt][r], 0.f));
            }
        }
        bf16x8 x2a = *(const bf16x8*)(XT + nl * 72 + rq * 8);
        bf16x8 x3a = *(const bf16x8*)(XT + nl * 72 + 32 + rq * 8);
        #pragma unroll
        for (int nt = 0; nt < 4; ++nt) {
            #pragma unroll
            for (int r = 0; r < 4; ++r) {
                float coef = __expf(xc2[nt][r]) * dinvv[nt];
                XT[(rq * 4 + r) * 72 + nt * 16 + nl] =
                    f2bu(coef * fmaxf(acc2t[nt][r], 0.f));
            }
        }
        bf16x8 x2b = *(const bf16x8*)(XT + nl * 72 + rq * 8);
        bf16x8 x3b = *(const bf16x8*)(XT + nl * 72 + 32 + rq * 8);

        // ---- layer V1 (B-frags shared) ----
        f32x4 va[4], vb[4];
        #pragma unroll
        for (int nt = 0; nt < 4; ++nt) {
            va[nt][0] = c1v[nt]; va[nt][1] = c1v[nt];
            va[nt][2] = c1v[nt]; va[nt][3] = c1v[nt];
            vb[nt] = va[nt];
        }
        #pragma unroll
        for (int nt = 0; nt < 4; ++nt) {
            bf16x8 b0 = *(const bf16x8*)(V1B + (0 * 4 + nt) * 640 + nl * 40 + rq * 8);
            va[nt] = MFMA16(a0, b0, va[nt], 0, 0, 0);
            vb[nt] = MFMA16(a2, b0, vb[nt], 0, 0, 0);
            bf16x8 b1 = *(const bf16x8*)(V1B + (1 * 4 + nt) * 640 + nl * 40 + rq * 8);
            va[nt] = MFMA16(a1, b1, va[nt], 0, 0, 0);
            vb[nt] = MFMA16(a3, b1, vb[nt], 0, 0, 0);
        }
        #pragma unroll
        for (int nt = 0; nt < 4; ++nt) {
            bf16x8 b2 = *(const bf16x8*)(V1B + (2 * 4 + nt) * 640 + nl * 40 + rq * 8);
            va[nt] = MFMA16(x2a, b2, va[nt], 0, 0, 0);
            vb[nt] = MFMA16(x2b, b2, vb[nt], 0, 0, 0);
            bf16x8 b3 = *(const bf16x8*)(V1B + (3 * 4 + nt) * 640 + nl * 40 + rq * 8);
            va[nt] = MFMA16(x3a, b3, va[nt], 0, 0, 0);
            vb[nt] = MFMA16(x3b, b3, vb[nt], 0, 0, 0);
        }
        // O1 epilogue tile1 -> XT, read o-frags; then tile2
        #pragma unroll
        for (int nt = 0; nt < 4; ++nt) {
            #pragma unroll
            for (int r = 0; r < 4; ++r)
                XT[(rq * 4 + r) * 72 + nt * 16 + nl] = f2bu(fmaxf(va[nt][r], 0.f));
        }
        bf16x8 o0a = *(const bf16x8*)(XT + nl * 72 + rq * 8);
        bf16x8 o1a = *(const bf16x8*)(XT + nl * 72 + 32 + rq * 8);
        #pragma unroll
        for (int nt = 0; nt < 4; ++nt) {
            #pragma unroll
            for (int r = 0; r < 4; ++r)
                XT[(rq * 4 + r) * 72 + nt * 16 + nl] = f2bu(fmaxf(vb[nt][r], 0.f));
        }
        bf16x8 o0b = *(const bf16x8*)(XT + nl * 72 + rq * 8);
        bf16x8 o1b = *(const bf16x8*)(XT + nl * 72 + 32 + rq * 8);

        // ---- layer V2 (B-frags shared) ----
        f32x4 wa[4], wb2[4];
        #pragma unroll
        for (int nt = 0; nt < 4; ++nt) {
            wa[nt][0] = c2v[nt]; wa[nt][1] = c2v[nt];
            wa[nt][2] = c2v[nt]; wa[nt][3] = c2v[nt];
            wb2[nt] = wa[nt];
        }
        #pragma unroll
        for (int nt = 0; nt < 4; ++nt) {
            bf16x8 b0 = *(const bf16x8*)(V2B + (0 * 4 + nt) * 640 + nl * 40 + rq * 8);
            wa[nt]  = MFMA16(o0a, b0, wa[nt], 0, 0, 0);
            wb2[nt] = MFMA16(o0b, b0, wb2[nt], 0, 0, 0);
            bf16x8 b1 = *(const bf16x8*)(V2B + (1 * 4 + nt) * 640 + nl * 40 + rq * 8);
            wa[nt]  = MFMA16(o1a, b1, wa[nt], 0, 0, 0);
            wb2[nt] = MFMA16(o1b, b1, wb2[nt], 0, 0, 0);
        }

        // ---- V3 + sigmoid, both tiles ----
        float sra[4], srb[4];
        #pragma unroll
        for (int r = 0; r < 4; ++r) {
            float u1 = 0.f, u2 = 0.f;
            #pragma unroll
            for (int nt = 0; nt < 4; ++nt) {
                u1 = fmaf(fmaxf(wa[nt][r],  0.f), v3v[nt], u1);
                u2 = fmaf(fmaxf(wb2[nt][r], 0.f), v3v[nt], u2);
            }
            u1 += __shfl_xor(u1, 1); u2 += __shfl_xor(u2, 1);
            u1 += __shfl_xor(u1, 2); u2 += __shfl_xor(u2, 2);
            u1 += __shfl_xor(u1, 4); u2 += __shfl_xor(u2, 4);
            u1 += __shfl_xor(u1, 8); u2 += __shfl_xor(u2, 8);
            sra[r] = u1; srb[r] = u2;
        }
        if (nl == 0) {
            #pragma unroll
            for (int r = 0; r < 4; ++r) {
                int ea = eB1 + rq * 4 + r;
                if (ea < e1) out[ea] = 1.f / (1.f + __expf(-(sra[r] + c3s)));
                int eb = eB2 + rq * 4 + r;
                if (eb < e1) out[eb] = 1.f / (1.f + __expf(-(srb[r] + c3s)));
            }
        }
    }
}

// ---------------------------------------------------------------------------
extern "C" void kernel_launch(void* const* d_in, const int* in_sizes, int n_in,
                              void* d_out, int out_size, void* d_ws, size_t ws_size,
                              hipStream_t stream) {
    const float* x     = (const float*)d_in[0];
    const float* u     = (const float*)d_in[1];
    const int*   batch = (const int*)  d_in[2];
    const int*   hidx  = (const int*)  d_in[3];
    const int*   bh    = (const int*)  d_in[4];
    const float* W1 = (const float*)d_in[6];
    const float* b1 = (const float*)d_in[7];
    const float* W2 = (const float*)d_in[8];
    const float* b2 = (const float*)d_in[9];
    const float* W3 = (const float*)d_in[10];
    const float* b3 = (const float*)d_in[11];
    const float* Wg = (const float*)d_in[12];
    const float* V1 = (const float*)d_in[13];
    const float* c1 = (const float*)d_in[14];
    const float* V2 = (const float*)d_in[15];
    const float* c2 = (const float*)d_in[16];
    const float* V3 = (const float*)d_in[17];
    const float* c3 = (const float*)d_in[18];

    const int N = in_sizes[0] / 6;
    const int G = in_sizes[1] / 4;
    const int E = in_sizes[4];

    // ws layout
    char* ws = (char*)d_ws;
    size_t off = 0;
    u16* hb = (u16*)(ws + off);            off += (size_t)N * 64 * 2;
    int* seg_start = (int*)(ws + off);     off += ((size_t)G + 1) * 4;
    off = (off + 255) & ~(size_t)255;
    u16* SWZ = (u16*)(ws + off);           off += 20480 * 2;
    float* Sinv = (float*)(ws + off);      off += (size_t)G * 64 * 4;
    off = (off + 255) & ~(size_t)255;
    u16* Xh = (u16*)(ws + off);            off += (size_t)E * 64 * 2;
    float* out = (float*)d_out;

    const int SB = (G + 256) / 256;
    const int NB = (N + 15) / 16;
    prep_mlp_kernel<<<32 + SB + NB, 256, 0, stream>>>(
        x, u, batch, W1, b1, W2, b2, W3, b3, hb, N,
        Wg, V1, V2, SWZ, bh, E, G, seg_start, SB);
    gather_stats_kernel<<<G, 256, 0, stream>>>(hb, hidx, seg_start, Xh, Sinv, out, E);
    mfma_seg_kernel<<<G, 256, 0, stream>>>(
        Xh, seg_start, SWZ, Sinv, c1, c2, V3, c3, out, E);
}

// Round 15
// 242.696 us; speedup vs baseline: 2.1276x; 1.0121x over previous
//
#include <hip/hip_runtime.h>
#include <math.h>

typedef short bf16x8 __attribute__((ext_vector_type(8)));
typedef float f32x4  __attribute__((ext_vector_type(4)));
typedef unsigned short u16;
typedef unsigned int   u32;

#define MFMA16 __builtin_amdgcn_mfma_f32_16x16x32_bf16

__device__ __forceinline__ u16 f2b(float x) {   // fp32 -> bf16 RNE
    union { float f; unsigned u; } v; v.f = x;
    unsigned r = v.u + 0x7fffu + ((v.u >> 16) & 1u);
    return (u16)(r >> 16);
}
// round-half-up bf16 (2 VALU vs 4; <=0.5ulp) — K4 Xhat/O1 quantization
__device__ __forceinline__ u16 f2bu(float x) {
    union { float f; unsigned u; } v; v.f = x;
    return (u16)((v.u + 0x8000u) >> 16);
}
__device__ __forceinline__ float b2f(u16 h) {
    union { unsigned u; float f; } v; v.u = ((unsigned)h) << 16;
    return v.f;
}
__device__ __forceinline__ float blo(u32 w) {
    union { u32 u; float f; } v; v.u = w << 16; return v.f;
}
__device__ __forceinline__ float bhi(u32 w) {
    union { u32 u; float f; } v; v.u = w & 0xffff0000u; return v.f;
}
// sum 3 packed bf16 pairs in fp32 (order i0+i1+i2), repack bf16 HALF-UP via
// one v_perm_b32 (R14-verified). exp and K4 A-frags both read the STORED value.
__device__ __forceinline__ u32 add3pack(u32 x, u32 y, u32 z) {
    union { float f; u32 u; } lo, hi;
    lo.f = blo(x) + blo(y) + blo(z);
    hi.f = bhi(x) + bhi(y) + bhi(z);
    return __builtin_amdgcn_perm(hi.u + 0x8000u, lo.u + 0x8000u, 0x07060302u);
}

#define LOG2E 1.44269504088896340736f

// ---------------------------------------------------------------------------
// K1 (merged, R14-verified): blocks [0,32) weight swizzle; [32,32+SB) segment
// bounds; rest node MLP -> hb (bf16). h bit-identical to R10.
// Panel(kt,nt): 16 n-rows x 40 u16. SWZ: WB[0,5120)|V1B[5120,15360)|V2B[15360,20480)
// ---------------------------------------------------------------------------
__global__ __launch_bounds__(256) void prep_mlp_kernel(
    const float* __restrict__ x, const float* __restrict__ u,
    const int* __restrict__ batch,
    const float* __restrict__ W1, const float* __restrict__ b1,
    const float* __restrict__ W2, const float* __restrict__ b2,
    const float* __restrict__ W3, const float* __restrict__ b3,
    u16* __restrict__ hb, int N,
    const float* __restrict__ Wg, const float* __restrict__ V1g,
    const float* __restrict__ V2g, u16* __restrict__ SWZ,
    const int* __restrict__ bh, int E, int G, int* __restrict__ seg_start,
    int SB)
{
    const int b = blockIdx.x, tid = threadIdx.x;
    if (b < 32) {                       // ---- weight swizzle ----
        int idx = b * 256 + tid;        // 0..8191
        int k = idx >> 6, n = idx & 63;
        int off = ((k >> 5) * 4 + (n >> 4)) * 640 + (n & 15) * 40 + ((k >> 3) & 3) * 8 + (k & 7);
        SWZ[5120 + off] = f2b(V1g[idx]);
        if (idx < 4096) {
            SWZ[off]         = f2b(Wg[idx]);
            SWZ[15360 + off] = f2b(V2g[idx]);
        }
        return;
    }
    if (b < 32 + SB) {                  // ---- segment bounds ----
        int g = (b - 32) * 256 + tid;
        if (g > G) return;
        int lo = 0, hi = E;
        while (lo < hi) {
            int mid = (lo + hi) >> 1;
            if (bh[mid] < g) lo = mid + 1; else hi = mid;
        }
        seg_start[g] = lo;
        return;
    }
    // ---- node MLP ----
    __shared__ float inbuf[16][10];
    __shared__ float h1[16][64];
    __shared__ float h2[16][64];
    const int ni = tid >> 6, f = tid & 63;
    const int base = (b - 32 - SB) * 16;
    int nodes[4];
    #pragma unroll
    for (int s = 0; s < 4; ++s) {
        nodes[s] = min(base + s * 4 + ni, N - 1);
        if (f < 6)       inbuf[s * 4 + ni][f] = x[nodes[s] * 6 + f];
        else if (f < 10) inbuf[s * 4 + ni][f] = u[batch[nodes[s]] * 4 + (f - 6)];
    }
    __syncthreads();
    float acc[4];
    #pragma unroll
    for (int s = 0; s < 4; ++s) acc[s] = b1[f];
    #pragma unroll
    for (int k = 0; k < 10; ++k) {
        float w = W1[k * 64 + f];
        #pragma unroll
        for (int s = 0; s < 4; ++s) acc[s] = fmaf(inbuf[s * 4 + ni][k], w, acc[s]);
    }
    #pragma unroll
    for (int s = 0; s < 4; ++s) h1[s * 4 + ni][f] = fmaxf(acc[s], 0.f);
    __syncthreads();
    #pragma unroll
    for (int s = 0; s < 4; ++s) acc[s] = b2[f];
    #pragma unroll
    for (int k4 = 0; k4 < 16; ++k4) {
        float w0 = W2[(k4 * 4 + 0) * 64 + f];
        float w1 = W2[(k4 * 4 + 1) * 64 + f];
        float w2 = W2[(k4 * 4 + 2) * 64 + f];
        float w3 = W2[(k4 * 4 + 3) * 64 + f];
        #pragma unroll
        for (int s = 0; s < 4; ++s) {
            float4 hv = *(const float4*)&h1[s * 4 + ni][k4 * 4];
            acc[s] = fmaf(hv.x, w0, acc[s]);
            acc[s] = fmaf(hv.y, w1, acc[s]);
            acc[s] = fmaf(hv.z, w2, acc[s]);
            acc[s] = fmaf(hv.w, w3, acc[s]);
        }
    }
    #pragma unroll
    for (int s = 0; s < 4; ++s) h2[s * 4 + ni][f] = fmaxf(acc[s], 0.f);
    __syncthreads();
    #pragma unroll
    for (int s = 0; s < 4; ++s) acc[s] = b3[f];
    #pragma unroll
    for (int k4 = 0; k4 < 16; ++k4) {
        float w0 = W3[(k4 * 4 + 0) * 64 + f];
        float w1 = W3[(k4 * 4 + 1) * 64 + f];
        float w2 = W3[(k4 * 4 + 2) * 64 + f];
        float w3 = W3[(k4 * 4 + 3) * 64 + f];
        #pragma unroll
        for (int s = 0; s < 4; ++s) {
            float4 hv = *(const float4*)&h2[s * 4 + ni][k4 * 4];
            acc[s] = fmaf(hv.x, w0, acc[s]);
            acc[s] = fmaf(hv.y, w1, acc[s]);
            acc[s] = fmaf(hv.z, w2, acc[s]);
            acc[s] = fmaf(hv.w, w3, acc[s]);
        }
    }
    #pragma unroll
    for (int s = 0; s < 4; ++s) hb[nodes[s] * 64 + f] = f2b(acc[s]);
}

// ---------------------------------------------------------------------------
// K3 (R14-verified): gather + Xh write + softmax denominators + out[E..2E).
// uint4 gathers, perm-based half-up pack. Standalone at high occupancy.
// ---------------------------------------------------------------------------
__global__ __launch_bounds__(256) void gather_stats_kernel(
    const u16* __restrict__ hb, const int* __restrict__ hidx,
    const int* __restrict__ seg_start,
    u16* __restrict__ Xh, float* __restrict__ Sinv,
    float* __restrict__ out, int E)
{
    __shared__ float ps[4][8][8];
    const int tid = threadIdx.x, lane = tid & 63, wid = tid >> 6;
    const int sub = lane >> 3, cl = lane & 7;
    const int g = blockIdx.x;
    const int e0 = seg_start[g], e1 = seg_start[g + 1];
    if (e1 <= e0) return;
    const int e1m1 = e1 - 1;
    const float gf = (float)g;

    for (int e = e0 + tid; e < e1; e += 256) out[E + e] = gf;

    float s[8] = {0.f, 0.f, 0.f, 0.f, 0.f, 0.f, 0.f, 0.f};
    for (int e = e0 + wid * 8 + sub; e < e1; e += 128) {
        #pragma unroll
        for (int j = 0; j < 4; ++j) {
            int ee = e + j * 32;
            int ec = min(ee, e1m1);
            int i0 = hidx[ec], i1 = hidx[E + ec], i2 = hidx[2 * E + ec];
            uint4 A0 = *(const uint4*)(hb + (size_t)i0 * 64 + cl * 8);
            uint4 A1 = *(const uint4*)(hb + (size_t)i1 * 64 + cl * 8);
            uint4 A2 = *(const uint4*)(hb + (size_t)i2 * 64 + cl * 8);
            u32 w0 = add3pack(A0.x, A1.x, A2.x);
            u32 w1 = add3pack(A0.y, A1.y, A2.y);
            u32 w2 = add3pack(A0.z, A1.z, A2.z);
            u32 w3 = add3pack(A0.w, A1.w, A2.w);
            if (ee < e1) {
                uint4 W; W.x = w0; W.y = w1; W.z = w2; W.w = w3;
                *(uint4*)(Xh + (size_t)ee * 64 + cl * 8) = W;
                s[0] += __expf(blo(w0)); s[1] += __expf(bhi(w0));
                s[2] += __expf(blo(w1)); s[3] += __expf(bhi(w1));
                s[4] += __expf(blo(w2)); s[5] += __expf(bhi(w2));
                s[6] += __expf(blo(w3)); s[7] += __expf(bhi(w3));
            }
        }
    }
    #pragma unroll
    for (int k = 0; k < 8; ++k) {
        s[k] += __shfl_xor(s[k], 8);
        s[k] += __shfl_xor(s[k], 16);
        s[k] += __shfl_xor(s[k], 32);
    }
    if (lane < 8) {
        #pragma unroll
        for (int k = 0; k < 8; ++k) ps[wid][lane][k] = s[k];
    }
    __syncthreads();
    if (tid < 64) {
        int c8 = tid >> 3, cc = tid & 7;
        float S = ps[0][c8][cc] + ps[1][c8][cc] + ps[2][c8][cc] + ps[3][c8][cc];
        Sinv[g * 64 + tid] = 1.f / S;
    }
}

// ---------------------------------------------------------------------------
// K4: paired-tile MFMA chain (R13-verified, 85us class). R15 deltas only:
//  - coef = exp2(xv*log2e + log2(dinv)): folds the dinv mul into the
//    exponent fma (saves ~64 VALU/pair-iter on the binding pipe).
//  - out-stores packed: 4 consecutive edges -> one float4 store from nl==0
//    (interior tiles; scalar fallback at segment tail).
// Locked: stride 72 (16B-aligned, R12/R13), f2bu epilogues, 256-thr +
// (256,3) (R9), weights in LDS (R5), Xh streamed w/ prefetch (R7).
// LDS: 40960(SW) + 9216(XT) = 50176 B -> 3 blocks/CU.
// ---------------------------------------------------------------------------
__global__ __launch_bounds__(256, 3) void mfma_seg_kernel(
    const u16* __restrict__ Xh, const int* __restrict__ seg_start,
    const u16* __restrict__ SWZ, const float* __restrict__ Sinv,
    const float* __restrict__ c1g, const float* __restrict__ c2g,
    const float* __restrict__ V3g, const float* __restrict__ c3g,
    float* __restrict__ out, int E)
{
    __shared__ u16 SW[20480];          // WB[0,5120)+V1B[5120,15360)+V2B[15360,20480)
    __shared__ u16 XT_all[4][16 * 72]; // per-wave transpose tile, stride 72

    const int tid = threadIdx.x, lane = tid & 63, wid = tid >> 6;
    const int nl = lane & 15, rq = lane >> 4;
    const int g = blockIdx.x;
    const int e0 = seg_start[g], e1 = seg_start[g + 1];
    const int L = e1 - e0;
    if (L <= 0) return;
    const int e1m1 = e1 - 1;

    {   // stage pre-swizzled W+V1+V2: 40960 B = 2560 uint4
        const uint4* src = (const uint4*)SWZ;
        uint4* dst = (uint4*)SW;
        for (int i = tid; i < 2560; i += 256) dst[i] = src[i];
    }
    __syncthreads();
    const u16* WB  = SW;
    const u16* V1B = SW + 5120;
    const u16* V2B = SW + 15360;

    // identity B-frags for X C-layout redistribution (exact in bf16)
    bf16x8 I0, I1;
    #pragma unroll
    for (int j = 0; j < 8; ++j) {
        I0[j] = (rq * 8 + j == nl)      ? (short)0x3F80 : (short)0;
        I1[j] = (rq * 8 + j == nl + 16) ? (short)0x3F80 : (short)0;
    }

    float l2d[4], c1v[4], c2v[4], v3v[4];
    #pragma unroll
    for (int nt = 0; nt < 4; ++nt) {
        int col = nt * 16 + nl;
        l2d[nt] = __log2f(Sinv[g * 64 + col]);   // log2(dinv), hoisted
        c1v[nt] = c1g[col];
        c2v[nt] = c2g[col];
        v3v[nt] = V3g[col];
    }
    const float c3s = c3g[0];
    u16* XT = XT_all[wid];
    const f32x4 zf = {0.f, 0.f, 0.f, 0.f};

    auto loadA = [&](int tt, bf16x8& A0, bf16x8& A1) {
        const u16* xp = Xh + (size_t)min(e0 + tt * 16 + nl, e1m1) * 64 + rq * 8;
        A0 = *(const bf16x8*)(xp);
        A1 = *(const bf16x8*)(xp + 32);
    };

    int t = wid;
    bf16x8 p0 = {}, p1 = {};
    if (t * 16 < L) loadA(t, p0, p1);

    for (; t * 16 < L; t += 8) {
        const int eB1 = e0 + t * 16;
        const int eB2 = eB1 + 64;                 // tile t+4 (may be phantom)

        bf16x8 a0 = p0, a1 = p1;                  // tile 1 (prefetched)
        bf16x8 a2, a3;
        loadA(t + 4, a2, a3);                     // tile 2 (clamped)
        if ((t + 8) * 16 < L) loadA(t + 8, p0, p1);  // prefetch next pair's 1st

        // xv in C-layout via identity MFMA, both tiles
        f32x4 xc1[4], xc2[4];
        xc1[0] = MFMA16(a0, I0, zf, 0, 0, 0);
        xc1[1] = MFMA16(a0, I1, zf, 0, 0, 0);
        xc1[2] = MFMA16(a1, I0, zf, 0, 0, 0);
        xc1[3] = MFMA16(a1, I1, zf, 0, 0, 0);
        xc2[0] = MFMA16(a2, I0, zf, 0, 0, 0);
        xc2[1] = MFMA16(a2, I1, zf, 0, 0, 0);
        xc2[2] = MFMA16(a3, I0, zf, 0, 0, 0);
        xc2[3] = MFMA16(a3, I1, zf, 0, 0, 0);

        // ---- layer W (B-frags shared) ----
        f32x4 acc1[4] = {zf, zf, zf, zf}, acc2t[4] = {zf, zf, zf, zf};
        #pragma unroll
        for (int nt = 0; nt < 4; ++nt) {
            bf16x8 b0 = *(const bf16x8*)(WB + (0 * 4 + nt) * 640 + nl * 40 + rq * 8);
            acc1[nt]  = MFMA16(a0, b0, acc1[nt], 0, 0, 0);
            acc2t[nt] = MFMA16(a2, b0, acc2t[nt], 0, 0, 0);
            bf16x8 b1 = *(const bf16x8*)(WB + (1 * 4 + nt) * 640 + nl * 40 + rq * 8);
            acc1[nt]  = MFMA16(a1, b1, acc1[nt], 0, 0, 0);
            acc2t[nt] = MFMA16(a3, b1, acc2t[nt], 0, 0, 0);
        }
        // Xhat epilogue: coef = exp2(xv*log2e + l2d)  [R15]
        #pragma unroll
        for (int nt = 0; nt < 4; ++nt) {
            #pragma unroll
            for (int r = 0; r < 4; ++r) {
                float coef = __builtin_amdgcn_exp2f(
                    fmaf(xc1[nt][r], LOG2E, l2d[nt]));
                XT[(rq * 4 + r) * 72 + nt * 16 + nl] =
                    f2bu(coef * fmaxf(acc1[nt][r], 0.f));
            }
        }
        bf16x8 x2a = *(const bf16x8*)(XT + nl * 72 + rq * 8);
        bf16x8 x3a = *(const bf16x8*)(XT + nl * 72 + 32 + rq * 8);
        #pragma unroll
        for (int nt = 0; nt < 4; ++nt) {
            #pragma unroll
            for (int r = 0; r < 4; ++r) {
                float coef = __builtin_amdgcn_exp2f(
                    fmaf(xc2[nt][r], LOG2E, l2d[nt]));
                XT[(rq * 4 + r) * 72 + nt * 16 + nl] =
                    f2bu(coef * fmaxf(acc2t[nt][r], 0.f));
            }
        }
        bf16x8 x2b = *(const bf16x8*)(XT + nl * 72 + rq * 8);
        bf16x8 x3b = *(const bf16x8*)(XT + nl * 72 + 32 + rq * 8);

        // ---- layer V1 (B-frags shared) ----
        f32x4 va[4], vb[4];
        #pragma unroll
        for (int nt = 0; nt < 4; ++nt) {
            va[nt][0] = c1v[nt]; va[nt][1] = c1v[nt];
            va[nt][2] = c1v[nt]; va[nt][3] = c1v[nt];
            vb[nt] = va[nt];
        }
        #pragma unroll
        for (int nt = 0; nt < 4; ++nt) {
            bf16x8 b0 = *(const bf16x8*)(V1B + (0 * 4 + nt) * 640 + nl * 40 + rq * 8);
            va[nt] = MFMA16(a0, b0, va[nt], 0, 0, 0);
            vb[nt] = MFMA16(a2, b0, vb[nt], 0, 0, 0);
            bf16x8 b1 = *(const bf16x8*)(V1B + (1 * 4 + nt) * 640 + nl * 40 + rq * 8);
            va[nt] = MFMA16(a1, b1, va[nt], 0, 0, 0);
            vb[nt] = MFMA16(a3, b1, vb[nt], 0, 0, 0);
        }
        #pragma unroll
        for (int nt = 0; nt < 4; ++nt) {
            bf16x8 b2 = *(const bf16x8*)(V1B + (2 * 4 + nt) * 640 + nl * 40 + rq * 8);
            va[nt] = MFMA16(x2a, b2, va[nt], 0, 0, 0);
            vb[nt] = MFMA16(x2b, b2, vb[nt], 0, 0, 0);
            bf16x8 b3 = *(const bf16x8*)(V1B + (3 * 4 + nt) * 640 + nl * 40 + rq * 8);
            va[nt] = MFMA16(x3a, b3, va[nt], 0, 0, 0);
            vb[nt] = MFMA16(x3b, b3, vb[nt], 0, 0, 0);
        }
        // O1 epilogue tile1 -> XT, read o-frags; then tile2
        #pragma unroll
        for (int nt = 0; nt < 4; ++nt) {
            #pragma unroll
            for (int r = 0; r < 4; ++r)
                XT[(rq * 4 + r) * 72 + nt * 16 + nl] = f2bu(fmaxf(va[nt][r], 0.f));
        }
        bf16x8 o0a = *(const bf16x8*)(XT + nl * 72 + rq * 8);
        bf16x8 o1a = *(const bf16x8*)(XT + nl * 72 + 32 + rq * 8);
        #pragma unroll
        for (int nt = 0; nt < 4; ++nt) {
            #pragma unroll
            for (int r = 0; r < 4; ++r)
                XT[(rq * 4 + r) * 72 + nt * 16 + nl] = f2bu(fmaxf(vb[nt][r], 0.f));
        }
        bf16x8 o0b = *(const bf16x8*)(XT + nl * 72 + rq * 8);
        bf16x8 o1b = *(const bf16x8*)(XT + nl * 72 + 32 + rq * 8);

        // ---- layer V2 (B-frags shared) ----
        f32x4 wa[4], wb2[4];
        #pragma unroll
        for (int nt = 0; nt < 4; ++nt) {
            wa[nt][0] = c2v[nt]; wa[nt][1] = c2v[nt];
            wa[nt][2] = c2v[nt]; wa[nt][3] = c2v[nt];
            wb2[nt] = wa[nt];
        }
        #pragma unroll
        for (int nt = 0; nt < 4; ++nt) {
            bf16x8 b0 = *(const bf16x8*)(V2B + (0 * 4 + nt) * 640 + nl * 40 + rq * 8);
            wa[nt]  = MFMA16(o0a, b0, wa[nt], 0, 0, 0);
            wb2[nt] = MFMA16(o0b, b0, wb2[nt], 0, 0, 0);
            bf16x8 b1 = *(const bf16x8*)(V2B + (1 * 4 + nt) * 640 + nl * 40 + rq * 8);
            wa[nt]  = MFMA16(o1a, b1, wa[nt], 0, 0, 0);
            wb2[nt] = MFMA16(o1b, b1, wb2[nt], 0, 0, 0);
        }

        // ---- V3 + sigmoid, both tiles ----
        float sra[4], srb[4];
        #pragma unroll
        for (int r = 0; r < 4; ++r) {
            float u1 = 0.f, u2 = 0.f;
            #pragma unroll
            for (int nt = 0; nt < 4; ++nt) {
                u1 = fmaf(fmaxf(wa[nt][r],  0.f), v3v[nt], u1);
                u2 = fmaf(fmaxf(wb2[nt][r], 0.f), v3v[nt], u2);
            }
            u1 += __shfl_xor(u1, 1); u2 += __shfl_xor(u2, 1);
            u1 += __shfl_xor(u1, 2); u2 += __shfl_xor(u2, 2);
            u1 += __shfl_xor(u1, 4); u2 += __shfl_xor(u2, 4);
            u1 += __shfl_xor(u1, 8); u2 += __shfl_xor(u2, 8);
            sra[r] = 1.f / (1.f + __expf(-(u1 + c3s)));
            srb[r] = 1.f / (1.f + __expf(-(u2 + c3s)));
        }
        if (nl == 0) {
            const int ra = eB1 + rq * 4;
            if (ra + 3 < e1) {                    // packed float4 store [R15]
                *(float4*)(out + ra) = make_float4(sra[0], sra[1], sra[2], sra[3]);
            } else {
                #pragma unroll
                for (int r = 0; r < 4; ++r)
                    if (ra + r < e1) out[ra + r] = sra[r];
            }
            const int rb = eB2 + rq * 4;
            if (rb + 3 < e1) {
                *(float4*)(out + rb) = make_float4(srb[0], srb[1], srb[2], srb[3]);
            } else {
                #pragma unroll
                for (int r = 0; r < 4; ++r)
                    if (rb + r < e1) out[rb + r] = srb[r];
            }
        }
    }
}

// ---------------------------------------------------------------------------
extern "C" void kernel_launch(void* const* d_in, const int* in_sizes, int n_in,
                              void* d_out, int out_size, void* d_ws, size_t ws_size,
                              hipStream_t stream) {
    const float* x     = (const float*)d_in[0];
    const float* u     = (const float*)d_in[1];
    const int*   batch = (const int*)  d_in[2];
    const int*   hidx  = (const int*)  d_in[3];
    const int*   bh    = (const int*)  d_in[4];
    const float* W1 = (const float*)d_in[6];
    const float* b1 = (const float*)d_in[7];
    const float* W2 = (const float*)d_in[8];
    const float* b2 = (const float*)d_in[9];
    const float* W3 = (const float*)d_in[10];
    const float* b3 = (const float*)d_in[11];
    const float* Wg = (const float*)d_in[12];
    const float* V1 = (const float*)d_in[13];
    const float* c1 = (const float*)d_in[14];
    const float* V2 = (const float*)d_in[15];
    const float* c2 = (const float*)d_in[16];
    const float* V3 = (const float*)d_in[17];
    const float* c3 = (const float*)d_in[18];

    const int N = in_sizes[0] / 6;
    const int G = in_sizes[1] / 4;
    const int E = in_sizes[4];

    // ws layout
    char* ws = (char*)d_ws;
    size_t off = 0;
    u16* hb = (u16*)(ws + off);            off += (size_t)N * 64 * 2;
    int* seg_start = (int*)(ws + off);     off += ((size_t)G + 1) * 4;
    off = (off + 255) & ~(size_t)255;
    u16* SWZ = (u16*)(ws + off);           off += 20480 * 2;
    float* Sinv = (float*)(ws + off);      off += (size_t)G * 64 * 4;
    off = (off + 255) & ~(size_t)255;
    u16* Xh = (u16*)(ws + off);            off += (size_t)E * 64 * 2;
    float* out = (float*)d_out;

    const int SB = (G + 256) / 256;
    const int NB = (N + 15) / 16;
    prep_mlp_kernel<<<32 + SB + NB, 256, 0, stream>>>(
        x, u, batch, W1, b1, W2, b2, W3, b3, hb, N,
        Wg, V1, V2, SWZ, bh, E, G, seg_start, SB);
    gather_stats_kernel<<<G, 256, 0, stream>>>(hb, hidx, seg_start, Xh, Sinv, out, E);
    mfma_seg_kernel<<<G, 256, 0, stream>>>(
        Xh, seg_start, SWZ, Sinv, c1, c2, V3, c3, out, E);
}